// Round 1
// baseline (5455.528 us; speedup 1.0000x reference)
//
#include <hip/hip_runtime.h>
#include <math.h>

#define HW 65536L

__device__ __forceinline__ int iabs_(int v) { return v < 0 ? -v : v; }

// ---------------- conv 1x1 (Cin=96) ----------------
// in: (B,96,HW) (mode 0) or attention-out permuted layout (mode 1)
// out: (B,Cout,HW). Weights (Cout,96) uniform -> scalar loads.
#define C1_PAD 108   // 96 + 12; 4*odd stride -> conflict-free b128, 16B aligned
__global__ __launch_bounds__(128) void conv1x1(
    const float* __restrict__ in, long in_bstride,
    const float* __restrict__ w,
    float* __restrict__ out, long out_bstride,
    int Cout, int mode)
{
  __shared__ float xs[128 * C1_PAD];
  const int t = threadIdx.x;
  const int p0 = blockIdx.x * 128;
  const int b = blockIdx.y;
  if (mode == 0) {
    const float* src = in + (long)b * in_bstride + p0 + t;
    #pragma unroll
    for (int cb = 0; cb < 24; cb++) {
      float4 v;
      v.x = src[(long)(cb*4+0) * HW];
      v.y = src[(long)(cb*4+1) * HW];
      v.z = src[(long)(cb*4+2) * HW];
      v.w = src[(long)(cb*4+3) * HW];
      *(float4*)&xs[t*C1_PAD + cb*4] = v;
    }
  } else {
    // input is attention output (B,4096,1536); spatial pixel p maps to
    // att[n][blk*96+ci], n=(y%64)*64+(x%64), blk=(y/64)*4+(x/64)
    const int p = p0 + t;
    const int py = p >> 8, px = p & 255;
    const float* src = in + (long)b * in_bstride
        + ((long)((py & 63)*64 + (px & 63)) * 16 + ((py >> 6)*4 + (px >> 6))) * 96;
    #pragma unroll
    for (int cb = 0; cb < 24; cb++) {
      *(float4*)&xs[t*C1_PAD + cb*4] = *(const float4*)&src[cb*4];
    }
  }
  __syncthreads();
  const int ng = Cout >> 3;
  for (int g = 0; g < ng; g++) {
    const float* wg = w + g*8*96;
    float acc[8];
    #pragma unroll
    for (int j = 0; j < 8; j++) acc[j] = 0.f;
    #pragma unroll 4
    for (int cb = 0; cb < 24; cb++) {
      float4 xv = *(const float4*)&xs[t*C1_PAD + cb*4];
      #pragma unroll
      for (int j = 0; j < 8; j++) {
        acc[j] = fmaf(wg[j*96 + cb*4+0], xv.x, acc[j]);
        acc[j] = fmaf(wg[j*96 + cb*4+1], xv.y, acc[j]);
        acc[j] = fmaf(wg[j*96 + cb*4+2], xv.z, acc[j]);
        acc[j] = fmaf(wg[j*96 + cb*4+3], xv.w, acc[j]);
      }
    }
    float* dst = out + (long)b * out_bstride + (long)(g*8) * HW + p0 + t;
    #pragma unroll
    for (int j = 0; j < 8; j++) dst[(long)j * HW] = acc[j];
  }
}

// ---------------- depthwise 3x3 pad 1 ----------------
__global__ __launch_bounds__(256) void dw3x3(
    const float* __restrict__ in, const float* __restrict__ w,
    float* __restrict__ out, int CH)
{
  const int t = threadIdx.x;
  const int p = blockIdx.x * 256 + t;
  const int ch = blockIdx.y, b = blockIdx.z;
  const int y = p >> 8, x = p & 255;
  const float* ip = in + (long)(b*CH + ch) * HW;
  const float* wp = w + ch*9;
  float acc = 0.f;
  #pragma unroll
  for (int dy = -1; dy <= 1; dy++) {
    int yy = y + dy;
    if (yy < 0 || yy > 255) continue;
    #pragma unroll
    for (int dx = -1; dx <= 1; dx++) {
      int xx = x + dx;
      if (xx < 0 || xx > 255) continue;
      acc = fmaf(ip[yy*256 + xx], wp[(dy+1)*3 + (dx+1)], acc);
    }
  }
  out[(long)(b*CH + ch) * HW + p] = acc;
}

// ---------------- depthwise 3x3 fused with v_s permutation ----------------
// in: (B,96,256,256) pre-dw; out: v_s (B,4096,1536)
// v_s[b][n][blk*96+ci] = dw(in)[b][ci][(blk>>2)*64 + n/64][(blk&3)*64 + n%64]
__global__ __launch_bounds__(256) void dw3x3_vs(
    const float* __restrict__ in, const float* __restrict__ w,
    float* __restrict__ vs)
{
  const int t = threadIdx.x;
  const int n = blockIdx.x, b = blockIdx.y;
  const int yy = n >> 6, xx = n & 63;
  float* orow = vs + ((long)b*4096 + n) * 1536;
  #pragma unroll
  for (int jd = 0; jd < 6; jd++) {
    int dd = jd*256 + t;
    int ci = dd % 96, blk = dd / 96;
    int iy = (blk >> 2)*64 + yy, ix = (blk & 3)*64 + xx;
    const float* ip = in + ((long)b*96 + ci) * HW;
    const float* wp = w + ci*9;
    float acc = 0.f;
    #pragma unroll
    for (int dy = -1; dy <= 1; dy++) {
      int y2 = iy + dy;
      if (y2 < 0 || y2 > 255) continue;
      #pragma unroll
      for (int dx = -1; dx <= 1; dx++) {
        int x2 = ix + dx;
        if (x2 < 0 || x2 > 255) continue;
        acc = fmaf(ip[y2*256 + x2], wp[(dy+1)*3 + (dx+1)], acc);
      }
    }
    orow[dd] = acc;
  }
}

// ---------------- depthwise 4x4 stride 4 pad 1 (256->64) ----------------
__global__ __launch_bounds__(256) void dw4x4s4(
    const float* __restrict__ in, const float* __restrict__ w,
    float* __restrict__ out)
{
  const int t = threadIdx.x;
  const int op = blockIdx.x * 256 + t;
  const int ch = blockIdx.y, b = blockIdx.z;
  const int oy = op >> 6, ox = op & 63;
  const float* ip = in + (long)(b*192 + ch) * HW;
  const float* wp = w + ch*16;
  float acc = 0.f;
  #pragma unroll
  for (int ty = 0; ty < 4; ty++) {
    int iy = 4*oy + ty - 1;
    if (iy < 0 || iy > 255) continue;
    #pragma unroll
    for (int tx = 0; tx < 4; tx++) {
      int ix = 4*ox + tx - 1;
      if (ix < 0 || ix > 255) continue;
      acc = fmaf(ip[iy*256 + ix], wp[ty*4 + tx], acc);
    }
  }
  out[(long)(b*192 + ch) * 4096 + op] = acc;
}

// ---------------- l2 norm over 192 channels + transpose to (B,4096,192) ----
__global__ __launch_bounds__(256) void l2n192(
    const float* __restrict__ in, float* __restrict__ out)
{
  const int t = threadIdx.x;
  const int wid = t >> 6, lane = t & 63;
  const int gw = blockIdx.x * 4 + wid;      // 0..8191
  const int b = gw >> 12, n = gw & 4095;
  const float* ip = in + (long)b * 786432;  // 192*4096
  float v0 = ip[(long)(lane      ) * 4096 + n];
  float v1 = ip[(long)(lane +  64) * 4096 + n];
  float v2 = ip[(long)(lane + 128) * 4096 + n];
  float ss = v0*v0 + v1*v1 + v2*v2;
  #pragma unroll
  for (int s = 1; s < 64; s <<= 1) ss += __shfl_xor(ss, s, 64);
  float nrm = fmaxf(sqrtf(ss), 1e-12f);
  float* op = out + ((long)b*4096 + n) * 192;
  op[lane      ] = v0 / nrm;
  op[lane +  64] = v1 / nrm;
  op[lane + 128] = v2 / nrm;
}

// ---------------- attention QK^T (one batch): (4096,192)x(4096,192)^T -----
__global__ __launch_bounds__(256) void attn_qk(
    const float* __restrict__ qn, const float* __restrict__ kn,
    float* __restrict__ attn, const float* __restrict__ tp)
{
  __shared__ float qs[8*192];
  const int t = threadIdx.x;
  const int r0 = blockIdx.x * 8;
  for (int i = t; i < 8*192; i += 256) qs[i] = qn[(long)r0*192 + i];
  __syncthreads();
  const float temp = tp[0];
  for (int mc = 0; mc < 2; mc++) {
    const float* kb = kn + (long)(mc*2048 + t) * 192;
    float acc[64];
    #pragma unroll
    for (int i = 0; i < 64; i++) acc[i] = 0.f;
    for (int cb = 0; cb < 48; cb++) {
      float4 kv[8];
      #pragma unroll
      for (int jm = 0; jm < 8; jm++)
        kv[jm] = *(const float4*)&kb[(long)jm*256*192 + cb*4];
      #pragma unroll
      for (int r = 0; r < 8; r++) {
        float4 qv = *(const float4*)&qs[r*192 + cb*4];
        #pragma unroll
        for (int jm = 0; jm < 8; jm++) {
          acc[r*8+jm] = fmaf(qv.x, kv[jm].x, acc[r*8+jm]);
          acc[r*8+jm] = fmaf(qv.y, kv[jm].y, acc[r*8+jm]);
          acc[r*8+jm] = fmaf(qv.z, kv[jm].z, acc[r*8+jm]);
          acc[r*8+jm] = fmaf(qv.w, kv[jm].w, acc[r*8+jm]);
        }
      }
    }
    #pragma unroll
    for (int r = 0; r < 8; r++)
      #pragma unroll
      for (int jm = 0; jm < 8; jm++)
        attn[(long)(r0+r)*4096 + mc*2048 + jm*256 + t] = acc[r*8+jm] * temp;
  }
}

// ------- top-5 + local mask + softmax + sparse out (one batch, one row/blk) -
__global__ __launch_bounds__(256) void attn_out_k(
    const float* __restrict__ attn, const float* __restrict__ vs,
    float* __restrict__ outr)
{
  __shared__ float row[4096];
  __shared__ float top5[256*5];
  __shared__ int   lm[4096];
  __shared__ float lw[4096];
  __shared__ float redf[8];
  __shared__ int   scan[256];
  const int t = threadIdx.x;
  const int n = blockIdx.x;
  const float* ar = attn + (long)n * 4096;
  #pragma unroll
  for (int k = 0; k < 16; k++) row[k*256 + t] = ar[k*256 + t];
  __syncthreads();
  // per-thread top-5 (sorted desc)
  float t0=-INFINITY,t1=-INFINITY,t2=-INFINITY,t3=-INFINITY,t4=-INFINITY;
  #pragma unroll
  for (int k = 0; k < 16; k++) {
    float v = row[k*256 + t];
    if (v > t4) {
      if (v > t0)      { t4=t3; t3=t2; t2=t1; t1=t0; t0=v; }
      else if (v > t1) { t4=t3; t3=t2; t2=t1; t1=v; }
      else if (v > t2) { t4=t3; t3=t2; t2=v; }
      else if (v > t3) { t4=t3; t3=v; }
      else             { t4=v; }
    }
  }
  top5[t*5+0]=t0; top5[t*5+1]=t1; top5[t*5+2]=t2; top5[t*5+3]=t3; top5[t*5+4]=t4;
  __syncthreads();
  for (int s = 128; s >= 1; s >>= 1) {
    if (t < s) {
      float* A = &top5[t*5];
      const float* B = &top5[(t+s)*5];
      float m[5]; int i = 0, j = 0;
      #pragma unroll
      for (int k = 0; k < 5; k++) {
        float av = A[i], bv = B[j];
        if (av >= bv) { m[k] = av; i++; } else { m[k] = bv; j++; }
      }
      #pragma unroll
      for (int k = 0; k < 5; k++) A[k] = m[k];
    }
    __syncthreads();
  }
  const float kth = top5[4];
  const int y = n >> 6, x = n & 63;
  // pass 1: count includes, local max
  int myc = 0;
  float wmax = -INFINITY;
  #pragma unroll
  for (int k = 0; k < 16; k++) {
    int m = k*256 + t;
    float a = row[m];
    int c = ((a >= kth) ? 1 : 0) +
            (((iabs_(y - (m >> 6)) + iabs_(x - (m & 63))) <= 4) ? 1 : 0);
    float wv = a * (float)c;
    if (wv != 0.0f) { myc++; wmax = fmaxf(wmax, wv); }
  }
  // exclusive scan (deterministic compaction)
  scan[t] = myc;
  __syncthreads();
  for (int s = 1; s < 256; s <<= 1) {
    int v = (t >= s) ? scan[t-s] : 0;
    __syncthreads();
    scan[t] += v;
    __syncthreads();
  }
  const int base = scan[t] - myc;
  const int cnt = scan[255];
  {
    int idx = base;
    #pragma unroll
    for (int k = 0; k < 16; k++) {
      int m = k*256 + t;
      float a = row[m];
      int c = ((a >= kth) ? 1 : 0) +
              (((iabs_(y - (m >> 6)) + iabs_(x - (m & 63))) <= 4) ? 1 : 0);
      float wv = a * (float)c;
      if (wv != 0.0f) { lm[idx] = m; lw[idx] = wv; idx++; }
    }
  }
  // block-reduce max
  #pragma unroll
  for (int s = 1; s < 64; s <<= 1) wmax = fmaxf(wmax, __shfl_xor(wmax, s, 64));
  if ((t & 63) == 0) redf[t >> 6] = wmax;
  __syncthreads();
  const float gmax = fmaxf(fmaxf(redf[0], redf[1]), fmaxf(redf[2], redf[3]));
  __syncthreads();
  // sum of exp
  float ps = 0.f;
  for (int i = t; i < cnt; i += 256) ps += expf(lw[i] - gmax);
  #pragma unroll
  for (int s = 1; s < 64; s <<= 1) ps += __shfl_xor(ps, s, 64);
  if ((t & 63) == 0) redf[4 + (t >> 6)] = ps;
  __syncthreads();
  const float S = redf[4] + redf[5] + redf[6] + redf[7];
  const float invS = 1.0f / S;
  // sparse accumulate against v_s
  float a0=0,a1=0,a2=0,a3=0,a4=0,a5=0;
  for (int e = 0; e < cnt; e++) {
    float se = expf(lw[e] - gmax) * invS;
    const float* vr = vs + (long)lm[e] * 1536;
    a0 = fmaf(se, vr[          t], a0);
    a1 = fmaf(se, vr[ 256 + t], a1);
    a2 = fmaf(se, vr[ 512 + t], a2);
    a3 = fmaf(se, vr[ 768 + t], a3);
    a4 = fmaf(se, vr[1024 + t], a4);
    a5 = fmaf(se, vr[1280 + t], a5);
  }
  float* orow = outr + (long)n * 1536;
  orow[          t] = a0;
  orow[ 256 + t] = a1;
  orow[ 512 + t] = a2;
  orow[ 768 + t] = a3;
  orow[1024 + t] = a4;
  orow[1280 + t] = a5;
}

// ---------------- per-channel l2 norm over 65536 (fhr q2/k2) ----------------
__global__ __launch_bounds__(1024) void l2n_sp(
    const float* __restrict__ in, float* __restrict__ out)
{
  const int ch = blockIdx.x, b = blockIdx.y, t = threadIdx.x;
  const float* ip = in + ((long)b*96 + ch) * HW;
  float ss = 0.f;
  for (int i = t; i < 65536; i += 1024) { float v = ip[i]; ss = fmaf(v, v, ss); }
  __shared__ float red[16];
  #pragma unroll
  for (int s = 1; s < 64; s <<= 1) ss += __shfl_xor(ss, s, 64);
  if ((t & 63) == 0) red[t >> 6] = ss;
  __syncthreads();
  if (t == 0) {
    float s2 = 0.f;
    for (int i = 0; i < 16; i++) s2 += red[i];
    red[0] = fmaxf(sqrtf(s2), 1e-12f);
  }
  __syncthreads();
  const float nrm = red[0];
  float* op = out + ((long)b*96 + ch) * HW;
  for (int i = t; i < 65536; i += 1024) op[i] = ip[i] / nrm;
}

// ---------------- a2 = softmax(q2n . k2n^T * temp) per (b,h,c) --------------
__global__ __launch_bounds__(256) void a2_kern(
    const float* __restrict__ q2n, const float* __restrict__ k2n,
    const float* __restrict__ temp, float* __restrict__ a2s)
{
  const int c = blockIdx.x, h = blockIdx.y, b = blockIdx.z, t = threadIdx.x;
  const float* q = q2n + ((long)b*96 + h*12 + c) * HW;
  const float* k = k2n + ((long)b*96 + h*12) * HW;
  float p[12];
  #pragma unroll
  for (int d = 0; d < 12; d++) p[d] = 0.f;
  for (int i = t; i < 65536; i += 256) {
    float qv = q[i];
    #pragma unroll
    for (int d = 0; d < 12; d++) p[d] = fmaf(qv, k[(long)d*HW + i], p[d]);
  }
  __shared__ float red[12*256];
  #pragma unroll
  for (int d = 0; d < 12; d++) red[d*256 + t] = p[d];
  __syncthreads();
  for (int s = 128; s >= 1; s >>= 1) {
    if (t < s) {
      #pragma unroll
      for (int d = 0; d < 12; d++) red[d*256 + t] += red[d*256 + t + s];
    }
    __syncthreads();
  }
  if (t == 0) {
    float tv = temp[h];
    float a[12], mx = -INFINITY;
    #pragma unroll
    for (int d = 0; d < 12; d++) { a[d] = red[d*256] * tv; mx = fmaxf(mx, a[d]); }
    float sum = 0.f;
    #pragma unroll
    for (int d = 0; d < 12; d++) { a[d] = expf(a[d] - mx); sum += a[d]; }
    float inv = 1.0f / sum;
    #pragma unroll
    for (int d = 0; d < 12; d++)
      a2s[(((long)b*8 + h)*12 + c)*12 + d] = a[d] * inv;
  }
}

// ---------------- o2pre = a2 @ v2 ----------------
__global__ __launch_bounds__(256) void o2pre_kern(
    const float* __restrict__ a2s, const float* __restrict__ v2,
    float* __restrict__ o2p)
{
  const int t = threadIdx.x;
  const int n = blockIdx.x * 256 + t;
  const int bh = blockIdx.y, b = bh >> 3, h = bh & 7;
  const float* a = a2s + (long)bh * 144;
  const float* vb = v2 + ((long)b*96 + h*12) * HW;
  float vv[12];
  #pragma unroll
  for (int d = 0; d < 12; d++) vv[d] = vb[(long)d*HW + n];
  float* ob = o2p + ((long)b*96 + h*12) * HW;
  #pragma unroll
  for (int c = 0; c < 12; c++) {
    float s = 0.f;
    #pragma unroll
    for (int d = 0; d < 12; d++) s = fmaf(a[c*12 + d], vv[d], s);
    ob[(long)c*HW + n] = s;
  }
}

extern "C" void kernel_launch(void* const* d_in, const int* in_sizes, int n_in,
                              void* d_out, int out_size, void* d_ws, size_t ws_size,
                              hipStream_t stream) {
  const float* x        = (const float*)d_in[0];
  const float* qk_w     = (const float*)d_in[1];
  const float* qk_dw    = (const float*)d_in[2];
  const float* v_w      = (const float*)d_in[3];
  const float* v_dw     = (const float*)d_in[4];
  const float* k2_w     = (const float*)d_in[5];
  const float* k2_dw    = (const float*)d_in[6];
  const float* q2_w     = (const float*)d_in[7];
  const float* q2_dw    = (const float*)d_in[8];
  const float* proj_w   = (const float*)d_in[9];
  const float* sab_temp = (const float*)d_in[10];
  const float* fqkv_w   = (const float*)d_in[11];
  const float* fqkv_dw  = (const float*)d_in[12];
  const float* fproj_w  = (const float*)d_in[13];
  const float* fhr_temp = (const float*)d_in[14];
  float* out = (float*)d_out;
  float* ws  = (float*)d_ws;

  // d_out regions (floats)
  float* O2  = out;               // (2,96,256,256)
  float* KS  = out + 12582912;    // (2,1,1,4096,192)  = normalized k
  float* VS  = out + 14155776;    // (2,1,1,4096,1536) = permuted v
  float* K2N = out + 26738688;    // (2,8,12,65536)    = normalized k2
  float* V2  = out + 39321600;    // (2,8,12,65536)    = raw v2

  // ws arena (floats); total 220 MB
  float* A0  = ws;                // 25165824
  float* A1  = ws + 25165824;     // 25165824
  float* QD  = ws + 50331648;     // 1572864
  float* KD  = ws + 51904512;     // 1572864
  float* QN  = ws + 53477376;     // 1572864
  float* A2S = ws + 55050240;     // 2304

  dim3 b128(128), b256(256), b1024(1024);

  // 1) y1_qk = 1x1(x, qk_w) -> A0 (2,192,HW)
  conv1x1<<<dim3(512,2), b128, 0, stream>>>(x, 96L*HW, qk_w, A0, 192L*HW, 192, 0);
  // 2) qk = dw3x3(y1_qk) -> A1 (2,192,HW); q=ch[0:96), k=ch[96:192)
  dw3x3<<<dim3(256,192,2), b256, 0, stream>>>(A0, qk_dw, A1, 192);
  // 3) y1_v = 1x1(x, v_w) -> A0 (2,96,HW)
  conv1x1<<<dim3(512,2), b128, 0, stream>>>(x, 96L*HW, v_w, A0, 96L*HW, 96, 0);
  // 4) v_s = permute(dw3x3(y1_v)) -> d_out
  dw3x3_vs<<<dim3(4096,2), b256, 0, stream>>>(A0, v_dw, VS);
  // 5) q2pre = 1x1(q, q2_w) -> A0 (2,192,HW)
  conv1x1<<<dim3(512,2), b128, 0, stream>>>(A1, 192L*HW, q2_w, A0, 192L*HW, 192, 0);
  // 6) qd = dw4x4s4(q2pre)
  dw4x4s4<<<dim3(16,192,2), b256, 0, stream>>>(A0, q2_dw, QD);
  // 7) k2pre = 1x1(k, k2_w) -> A0
  conv1x1<<<dim3(512,2), b128, 0, stream>>>(A1 + 96L*HW, 192L*HW, k2_w, A0, 192L*HW, 192, 0);
  // 8) kd = dw4x4s4(k2pre)
  dw4x4s4<<<dim3(16,192,2), b256, 0, stream>>>(A0, k2_dw, KD);
  // 9/10) l2norm + transpose -> qn (ws), kn (d_out k_s)
  l2n192<<<dim3(2048), b256, 0, stream>>>(QD, QN);
  l2n192<<<dim3(2048), b256, 0, stream>>>(KD, KS);
  // 11) attention, per batch (attn materialized in A0, 4096x4096)
  for (int b = 0; b < 2; b++) {
    attn_qk<<<dim3(512), b256, 0, stream>>>(
        QN + (long)b*786432, KS + (long)b*786432, A0, sab_temp);
    attn_out_k<<<dim3(4096), b256, 0, stream>>>(
        A0, VS + (long)b*6291456, A1 + (long)b*6291456);
  }
  // 12) aligned = 1x1(permuted attn-out, proj_w) -> A0[0:12.58M]
  conv1x1<<<dim3(512,2), b128, 0, stream>>>(A1, 6291456L, proj_w, A0, 96L*HW, 96, 1);
  // 13-15) fhr qkv: three sequential 96-ch paths
  float* PRE  = A0 + 12582912;
  float* DW1  = A1 + 12582912;
  float* Q2NB = A1;
  // q2
  conv1x1<<<dim3(512,2), b128, 0, stream>>>(A0, 96L*HW, fqkv_w,        PRE, 96L*HW, 96, 0);
  dw3x3<<<dim3(256,96,2), b256, 0, stream>>>(PRE, fqkv_dw,        DW1, 96);
  l2n_sp<<<dim3(96,2), b1024, 0, stream>>>(DW1, Q2NB);
  // k2
  conv1x1<<<dim3(512,2), b128, 0, stream>>>(A0, 96L*HW, fqkv_w +  9216, PRE, 96L*HW, 96, 0);
  dw3x3<<<dim3(256,96,2), b256, 0, stream>>>(PRE, fqkv_dw +  864, DW1, 96);
  l2n_sp<<<dim3(96,2), b1024, 0, stream>>>(DW1, K2N);
  // v2 (raw dw output is the v2 output layout directly)
  conv1x1<<<dim3(512,2), b128, 0, stream>>>(A0, 96L*HW, fqkv_w + 18432, PRE, 96L*HW, 96, 0);
  dw3x3<<<dim3(256,96,2), b256, 0, stream>>>(PRE, fqkv_dw + 1728, V2, 96);
  // 16) a2 = softmax(q2n.k2n^T * fhr_temp)
  a2_kern<<<dim3(12,8,2), b256, 0, stream>>>(Q2NB, K2N, fhr_temp, A2S);
  // 17) o2pre = a2 @ v2 -> A0
  o2pre_kern<<<dim3(256,16), b256, 0, stream>>>(A2S, V2, A0);
  // 18) o2 = 1x1(o2pre, fproj_w) -> d_out
  conv1x1<<<dim3(512,2), b128, 0, stream>>>(A0, 96L*HW, fproj_w, O2, 96L*HW, 96, 0);
}

// Round 2
// 3084.376 us; speedup vs baseline: 1.7688x; 1.7688x over previous
//
#include <hip/hip_runtime.h>
#include <math.h>

#define HW 65536L

__device__ __forceinline__ int iabs_(int v) { return v < 0 ? -v : v; }

// ---------------- conv 1x1 (Cin=96), register-resident, no LDS ----------------
// in: (B,96,HW) (mode 0) or attention-out permuted layout (mode 1)
// out: (B,Cout,HW). Weights block-uniform -> scalar loads (s_load + v_fmac).
__global__ __launch_bounds__(256) void conv1x1(
    const float* __restrict__ in, long in_bstride,
    const float* __restrict__ w,
    float* __restrict__ out, long out_bstride,
    int Cout, int mode)
{
  const int t = threadIdx.x;
  const int p = blockIdx.x * 256 + t;
  const int b = blockIdx.y;
  float x[96];
  if (mode == 0) {
    const float* src = in + (long)b * in_bstride + p;
    #pragma unroll
    for (int c = 0; c < 96; c++) x[c] = src[(long)c * HW];
  } else {
    // input is attention output (B,4096,1536); spatial pixel p maps to
    // att[n][blk*96+ci], n=(y%64)*64+(x%64), blk=(y/64)*4+(x/64)
    const int py = p >> 8, px = p & 255;
    const float* src = in + (long)b * in_bstride
        + ((long)((py & 63)*64 + (px & 63)) * 16 + ((py >> 6)*4 + (px >> 6))) * 96;
    #pragma unroll
    for (int cb = 0; cb < 24; cb++) {
      float4 v = *(const float4*)&src[cb*4];
      x[cb*4+0] = v.x; x[cb*4+1] = v.y; x[cb*4+2] = v.z; x[cb*4+3] = v.w;
    }
  }
  float* dst = out + (long)b * out_bstride + p;
  const int ng = Cout >> 3;
  for (int g = 0; g < ng; g++) {
    const float* wg = w + g*8*96;
    float acc[8];
    #pragma unroll
    for (int j = 0; j < 8; j++) acc[j] = 0.f;
    #pragma unroll
    for (int k = 0; k < 96; k++) {
      float xv = x[k];
      #pragma unroll
      for (int j = 0; j < 8; j++) acc[j] = fmaf(wg[j*96 + k], xv, acc[j]);
    }
    #pragma unroll
    for (int j = 0; j < 8; j++) dst[(long)(g*8 + j) * HW] = acc[j];
  }
}

// ---------------- depthwise 3x3 pad 1 ----------------
__global__ __launch_bounds__(256) void dw3x3(
    const float* __restrict__ in, const float* __restrict__ w,
    float* __restrict__ out, int CH)
{
  const int t = threadIdx.x;
  const int p = blockIdx.x * 256 + t;
  const int ch = blockIdx.y, b = blockIdx.z;
  const int y = p >> 8, x = p & 255;
  const float* ip = in + (long)(b*CH + ch) * HW;
  const float* wp = w + ch*9;
  float acc = 0.f;
  #pragma unroll
  for (int dy = -1; dy <= 1; dy++) {
    int yy = y + dy;
    if (yy < 0 || yy > 255) continue;
    #pragma unroll
    for (int dx = -1; dx <= 1; dx++) {
      int xx = x + dx;
      if (xx < 0 || xx > 255) continue;
      acc = fmaf(ip[yy*256 + xx], wp[(dy+1)*3 + (dx+1)], acc);
    }
  }
  out[(long)(b*CH + ch) * HW + p] = acc;
}

// ---------------- depthwise 3x3 fused with v_s permutation ----------------
// in: (B,96,256,256) pre-dw; out: v_s (B,4096,1536)
// v_s[b][n][blk*96+ci] = dw(in)[b][ci][(blk>>2)*64 + n/64][(blk&3)*64 + n%64]
__global__ __launch_bounds__(256) void dw3x3_vs(
    const float* __restrict__ in, const float* __restrict__ w,
    float* __restrict__ vs)
{
  const int t = threadIdx.x;
  const int n = blockIdx.x, b = blockIdx.y;
  const int yy = n >> 6, xx = n & 63;
  float* orow = vs + ((long)b*4096 + n) * 1536;
  #pragma unroll
  for (int jd = 0; jd < 6; jd++) {
    int dd = jd*256 + t;
    int ci = dd % 96, blk = dd / 96;
    int iy = (blk >> 2)*64 + yy, ix = (blk & 3)*64 + xx;
    const float* ip = in + ((long)b*96 + ci) * HW;
    const float* wp = w + ci*9;
    float acc = 0.f;
    #pragma unroll
    for (int dy = -1; dy <= 1; dy++) {
      int y2 = iy + dy;
      if (y2 < 0 || y2 > 255) continue;
      #pragma unroll
      for (int dx = -1; dx <= 1; dx++) {
        int x2 = ix + dx;
        if (x2 < 0 || x2 > 255) continue;
        acc = fmaf(ip[y2*256 + x2], wp[(dy+1)*3 + (dx+1)], acc);
      }
    }
    orow[dd] = acc;
  }
}

// ---------------- depthwise 4x4 stride 4 pad 1 (256->64) ----------------
__global__ __launch_bounds__(256) void dw4x4s4(
    const float* __restrict__ in, const float* __restrict__ w,
    float* __restrict__ out)
{
  const int t = threadIdx.x;
  const int op = blockIdx.x * 256 + t;
  const int ch = blockIdx.y, b = blockIdx.z;
  const int oy = op >> 6, ox = op & 63;
  const float* ip = in + (long)(b*192 + ch) * HW;
  const float* wp = w + ch*16;
  float acc = 0.f;
  #pragma unroll
  for (int ty = 0; ty < 4; ty++) {
    int iy = 4*oy + ty - 1;
    if (iy < 0 || iy > 255) continue;
    #pragma unroll
    for (int tx = 0; tx < 4; tx++) {
      int ix = 4*ox + tx - 1;
      if (ix < 0 || ix > 255) continue;
      acc = fmaf(ip[iy*256 + ix], wp[ty*4 + tx], acc);
    }
  }
  out[(long)(b*192 + ch) * 4096 + op] = acc;
}

// ---------------- l2 norm over 192 channels + transpose to (B,4096,192) ----
__global__ __launch_bounds__(256) void l2n192(
    const float* __restrict__ in, float* __restrict__ out)
{
  const int t = threadIdx.x;
  const int wid = t >> 6, lane = t & 63;
  const int gw = blockIdx.x * 4 + wid;      // 0..8191
  const int b = gw >> 12, n = gw & 4095;
  const float* ip = in + (long)b * 786432;  // 192*4096
  float v0 = ip[(long)(lane      ) * 4096 + n];
  float v1 = ip[(long)(lane +  64) * 4096 + n];
  float v2 = ip[(long)(lane + 128) * 4096 + n];
  float ss = v0*v0 + v1*v1 + v2*v2;
  #pragma unroll
  for (int s = 1; s < 64; s <<= 1) ss += __shfl_xor(ss, s, 64);
  float nrm = fmaxf(sqrtf(ss), 1e-12f);
  float* op = out + ((long)b*4096 + n) * 192;
  op[lane      ] = v0 / nrm;
  op[lane +  64] = v1 / nrm;
  op[lane + 128] = v2 / nrm;
}

// ---------------- attention QK^T (one batch): (4096,192)x(4096,192)^T -----
__global__ __launch_bounds__(256) void attn_qk(
    const float* __restrict__ qn, const float* __restrict__ kn,
    float* __restrict__ attn, const float* __restrict__ tp)
{
  __shared__ float qs[8*192];
  const int t = threadIdx.x;
  const int r0 = blockIdx.x * 8;
  for (int i = t; i < 8*192; i += 256) qs[i] = qn[(long)r0*192 + i];
  __syncthreads();
  const float temp = tp[0];
  for (int mc = 0; mc < 2; mc++) {
    const float* kb = kn + (long)(mc*2048 + t) * 192;
    float acc[64];
    #pragma unroll
    for (int i = 0; i < 64; i++) acc[i] = 0.f;
    for (int cb = 0; cb < 48; cb++) {
      float4 kv[8];
      #pragma unroll
      for (int jm = 0; jm < 8; jm++)
        kv[jm] = *(const float4*)&kb[(long)jm*256*192 + cb*4];
      #pragma unroll
      for (int r = 0; r < 8; r++) {
        float4 qv = *(const float4*)&qs[r*192 + cb*4];
        #pragma unroll
        for (int jm = 0; jm < 8; jm++) {
          acc[r*8+jm] = fmaf(qv.x, kv[jm].x, acc[r*8+jm]);
          acc[r*8+jm] = fmaf(qv.y, kv[jm].y, acc[r*8+jm]);
          acc[r*8+jm] = fmaf(qv.z, kv[jm].z, acc[r*8+jm]);
          acc[r*8+jm] = fmaf(qv.w, kv[jm].w, acc[r*8+jm]);
        }
      }
    }
    #pragma unroll
    for (int r = 0; r < 8; r++)
      #pragma unroll
      for (int jm = 0; jm < 8; jm++)
        attn[(long)(r0+r)*4096 + mc*2048 + jm*256 + t] = acc[r*8+jm] * temp;
  }
}

// ------- top-5 + local mask + softmax + sparse out (one batch, one row/blk) -
__global__ __launch_bounds__(256) void attn_out_k(
    const float* __restrict__ attn, const float* __restrict__ vs,
    float* __restrict__ outr)
{
  __shared__ float row[4096];
  __shared__ float top5[256*5];
  __shared__ int   lm[4096];
  __shared__ float lw[4096];
  __shared__ float redf[8];
  __shared__ int   scan[256];
  const int t = threadIdx.x;
  const int n = blockIdx.x;
  const float* ar = attn + (long)n * 4096;
  #pragma unroll
  for (int k = 0; k < 16; k++) row[k*256 + t] = ar[k*256 + t];
  __syncthreads();
  // per-thread top-5 (sorted desc)
  float t0=-INFINITY,t1=-INFINITY,t2=-INFINITY,t3=-INFINITY,t4=-INFINITY;
  #pragma unroll
  for (int k = 0; k < 16; k++) {
    float v = row[k*256 + t];
    if (v > t4) {
      if (v > t0)      { t4=t3; t3=t2; t2=t1; t1=t0; t0=v; }
      else if (v > t1) { t4=t3; t3=t2; t2=t1; t1=v; }
      else if (v > t2) { t4=t3; t3=t2; t2=v; }
      else if (v > t3) { t4=t3; t3=v; }
      else             { t4=v; }
    }
  }
  top5[t*5+0]=t0; top5[t*5+1]=t1; top5[t*5+2]=t2; top5[t*5+3]=t3; top5[t*5+4]=t4;
  __syncthreads();
  for (int s = 128; s >= 1; s >>= 1) {
    if (t < s) {
      float* A = &top5[t*5];
      const float* B = &top5[(t+s)*5];
      float m[5]; int i = 0, j = 0;
      #pragma unroll
      for (int k = 0; k < 5; k++) {
        float av = A[i], bv = B[j];
        if (av >= bv) { m[k] = av; i++; } else { m[k] = bv; j++; }
      }
      #pragma unroll
      for (int k = 0; k < 5; k++) A[k] = m[k];
    }
    __syncthreads();
  }
  const float kth = top5[4];
  const int y = n >> 6, x = n & 63;
  // pass 1: count includes, local max
  int myc = 0;
  float wmax = -INFINITY;
  #pragma unroll
  for (int k = 0; k < 16; k++) {
    int m = k*256 + t;
    float a = row[m];
    int c = ((a >= kth) ? 1 : 0) +
            (((iabs_(y - (m >> 6)) + iabs_(x - (m & 63))) <= 4) ? 1 : 0);
    float wv = a * (float)c;
    if (wv != 0.0f) { myc++; wmax = fmaxf(wmax, wv); }
  }
  // exclusive scan (deterministic compaction)
  scan[t] = myc;
  __syncthreads();
  for (int s = 1; s < 256; s <<= 1) {
    int v = (t >= s) ? scan[t-s] : 0;
    __syncthreads();
    scan[t] += v;
    __syncthreads();
  }
  const int base = scan[t] - myc;
  const int cnt = scan[255];
  {
    int idx = base;
    #pragma unroll
    for (int k = 0; k < 16; k++) {
      int m = k*256 + t;
      float a = row[m];
      int c = ((a >= kth) ? 1 : 0) +
              (((iabs_(y - (m >> 6)) + iabs_(x - (m & 63))) <= 4) ? 1 : 0);
      float wv = a * (float)c;
      if (wv != 0.0f) { lm[idx] = m; lw[idx] = wv; idx++; }
    }
  }
  // block-reduce max
  #pragma unroll
  for (int s = 1; s < 64; s <<= 1) wmax = fmaxf(wmax, __shfl_xor(wmax, s, 64));
  if ((t & 63) == 0) redf[t >> 6] = wmax;
  __syncthreads();
  const float gmax = fmaxf(fmaxf(redf[0], redf[1]), fmaxf(redf[2], redf[3]));
  __syncthreads();
  // sum of exp
  float ps = 0.f;
  for (int i = t; i < cnt; i += 256) ps += expf(lw[i] - gmax);
  #pragma unroll
  for (int s = 1; s < 64; s <<= 1) ps += __shfl_xor(ps, s, 64);
  if ((t & 63) == 0) redf[4 + (t >> 6)] = ps;
  __syncthreads();
  const float S = redf[4] + redf[5] + redf[6] + redf[7];
  const float invS = 1.0f / S;
  // sparse accumulate against v_s
  float a0=0,a1=0,a2=0,a3=0,a4=0,a5=0;
  for (int e = 0; e < cnt; e++) {
    float se = expf(lw[e] - gmax) * invS;
    const float* vr = vs + (long)lm[e] * 1536;
    a0 = fmaf(se, vr[          t], a0);
    a1 = fmaf(se, vr[ 256 + t], a1);
    a2 = fmaf(se, vr[ 512 + t], a2);
    a3 = fmaf(se, vr[ 768 + t], a3);
    a4 = fmaf(se, vr[1024 + t], a4);
    a5 = fmaf(se, vr[1280 + t], a5);
  }
  float* orow = outr + (long)n * 1536;
  orow[          t] = a0;
  orow[ 256 + t] = a1;
  orow[ 512 + t] = a2;
  orow[ 768 + t] = a3;
  orow[1024 + t] = a4;
  orow[1280 + t] = a5;
}

// ---------------- per-channel l2 norm over 65536 (fhr q2/k2) ----------------
__global__ __launch_bounds__(1024) void l2n_sp(
    const float* __restrict__ in, float* __restrict__ out)
{
  const int ch = blockIdx.x, b = blockIdx.y, t = threadIdx.x;
  const float* ip = in + ((long)b*96 + ch) * HW;
  float ss = 0.f;
  for (int i = t; i < 65536; i += 1024) { float v = ip[i]; ss = fmaf(v, v, ss); }
  __shared__ float red[16];
  #pragma unroll
  for (int s = 1; s < 64; s <<= 1) ss += __shfl_xor(ss, s, 64);
  if ((t & 63) == 0) red[t >> 6] = ss;
  __syncthreads();
  if (t == 0) {
    float s2 = 0.f;
    for (int i = 0; i < 16; i++) s2 += red[i];
    red[0] = fmaxf(sqrtf(s2), 1e-12f);
  }
  __syncthreads();
  const float nrm = red[0];
  float* op = out + ((long)b*96 + ch) * HW;
  for (int i = t; i < 65536; i += 1024) op[i] = ip[i] / nrm;
}

// ---------------- a2 = softmax(q2n . k2n^T * temp) per (b,h,c) --------------
__global__ __launch_bounds__(256) void a2_kern(
    const float* __restrict__ q2n, const float* __restrict__ k2n,
    const float* __restrict__ temp, float* __restrict__ a2s)
{
  const int c = blockIdx.x, h = blockIdx.y, b = blockIdx.z, t = threadIdx.x;
  const float* q = q2n + ((long)b*96 + h*12 + c) * HW;
  const float* k = k2n + ((long)b*96 + h*12) * HW;
  float p[12];
  #pragma unroll
  for (int d = 0; d < 12; d++) p[d] = 0.f;
  for (int i = t; i < 65536; i += 256) {
    float qv = q[i];
    #pragma unroll
    for (int d = 0; d < 12; d++) p[d] = fmaf(qv, k[(long)d*HW + i], p[d]);
  }
  __shared__ float red[12*256];
  #pragma unroll
  for (int d = 0; d < 12; d++) red[d*256 + t] = p[d];
  __syncthreads();
  for (int s = 128; s >= 1; s >>= 1) {
    if (t < s) {
      #pragma unroll
      for (int d = 0; d < 12; d++) red[d*256 + t] += red[d*256 + t + s];
    }
    __syncthreads();
  }
  if (t == 0) {
    float tv = temp[h];
    float a[12], mx = -INFINITY;
    #pragma unroll
    for (int d = 0; d < 12; d++) { a[d] = red[d*256] * tv; mx = fmaxf(mx, a[d]); }
    float sum = 0.f;
    #pragma unroll
    for (int d = 0; d < 12; d++) { a[d] = expf(a[d] - mx); sum += a[d]; }
    float inv = 1.0f / sum;
    #pragma unroll
    for (int d = 0; d < 12; d++)
      a2s[(((long)b*8 + h)*12 + c)*12 + d] = a[d] * inv;
  }
}

// ---------------- o2pre = a2 @ v2 ----------------
__global__ __launch_bounds__(256) void o2pre_kern(
    const float* __restrict__ a2s, const float* __restrict__ v2,
    float* __restrict__ o2p)
{
  const int t = threadIdx.x;
  const int n = blockIdx.x * 256 + t;
  const int bh = blockIdx.y, b = bh >> 3, h = bh & 7;
  const float* a = a2s + (long)bh * 144;
  const float* vb = v2 + ((long)b*96 + h*12) * HW;
  float vv[12];
  #pragma unroll
  for (int d = 0; d < 12; d++) vv[d] = vb[(long)d*HW + n];
  float* ob = o2p + ((long)b*96 + h*12) * HW;
  #pragma unroll
  for (int c = 0; c < 12; c++) {
    float s = 0.f;
    #pragma unroll
    for (int d = 0; d < 12; d++) s = fmaf(a[c*12 + d], vv[d], s);
    ob[(long)c*HW + n] = s;
  }
}

extern "C" void kernel_launch(void* const* d_in, const int* in_sizes, int n_in,
                              void* d_out, int out_size, void* d_ws, size_t ws_size,
                              hipStream_t stream) {
  const float* x        = (const float*)d_in[0];
  const float* qk_w     = (const float*)d_in[1];
  const float* qk_dw    = (const float*)d_in[2];
  const float* v_w      = (const float*)d_in[3];
  const float* v_dw     = (const float*)d_in[4];
  const float* k2_w     = (const float*)d_in[5];
  const float* k2_dw    = (const float*)d_in[6];
  const float* q2_w     = (const float*)d_in[7];
  const float* q2_dw    = (const float*)d_in[8];
  const float* proj_w   = (const float*)d_in[9];
  const float* sab_temp = (const float*)d_in[10];
  const float* fqkv_w   = (const float*)d_in[11];
  const float* fqkv_dw  = (const float*)d_in[12];
  const float* fproj_w  = (const float*)d_in[13];
  const float* fhr_temp = (const float*)d_in[14];
  float* out = (float*)d_out;
  float* ws  = (float*)d_ws;

  // d_out regions (floats)
  float* O2  = out;               // (2,96,256,256)
  float* KS  = out + 12582912;    // (2,1,1,4096,192)  = normalized k
  float* VS  = out + 14155776;    // (2,1,1,4096,1536) = permuted v
  float* K2N = out + 26738688;    // (2,8,12,65536)    = normalized k2
  float* V2  = out + 39321600;    // (2,8,12,65536)    = raw v2

  // ws arena (floats); total 220 MB
  float* A0  = ws;                // 25165824
  float* A1  = ws + 25165824;     // 25165824
  float* QD  = ws + 50331648;     // 1572864
  float* KD  = ws + 51904512;     // 1572864
  float* QN  = ws + 53477376;     // 1572864
  float* A2S = ws + 55050240;     // 2304

  dim3 b256(256), b1024(1024);

  // 1) y1_qk = 1x1(x, qk_w) -> A0 (2,192,HW)
  conv1x1<<<dim3(256,2), b256, 0, stream>>>(x, 96L*HW, qk_w, A0, 192L*HW, 192, 0);
  // 2) qk = dw3x3(y1_qk) -> A1 (2,192,HW); q=ch[0:96), k=ch[96:192)
  dw3x3<<<dim3(256,192,2), b256, 0, stream>>>(A0, qk_dw, A1, 192);
  // 3) y1_v = 1x1(x, v_w) -> A0 (2,96,HW)
  conv1x1<<<dim3(256,2), b256, 0, stream>>>(x, 96L*HW, v_w, A0, 96L*HW, 96, 0);
  // 4) v_s = permute(dw3x3(y1_v)) -> d_out
  dw3x3_vs<<<dim3(4096,2), b256, 0, stream>>>(A0, v_dw, VS);
  // 5) q2pre = 1x1(q, q2_w) -> A0 (2,192,HW)
  conv1x1<<<dim3(256,2), b256, 0, stream>>>(A1, 192L*HW, q2_w, A0, 192L*HW, 192, 0);
  // 6) qd = dw4x4s4(q2pre)
  dw4x4s4<<<dim3(16,192,2), b256, 0, stream>>>(A0, q2_dw, QD);
  // 7) k2pre = 1x1(k, k2_w) -> A0
  conv1x1<<<dim3(256,2), b256, 0, stream>>>(A1 + 96L*HW, 192L*HW, k2_w, A0, 192L*HW, 192, 0);
  // 8) kd = dw4x4s4(k2pre)
  dw4x4s4<<<dim3(16,192,2), b256, 0, stream>>>(A0, k2_dw, KD);
  // 9/10) l2norm + transpose -> qn (ws), kn (d_out k_s)
  l2n192<<<dim3(2048), b256, 0, stream>>>(QD, QN);
  l2n192<<<dim3(2048), b256, 0, stream>>>(KD, KS);
  // 11) attention, per batch (attn materialized in A0, 4096x4096)
  for (int b = 0; b < 2; b++) {
    attn_qk<<<dim3(512), b256, 0, stream>>>(
        QN + (long)b*786432, KS + (long)b*786432, A0, sab_temp);
    attn_out_k<<<dim3(4096), b256, 0, stream>>>(
        A0, VS + (long)b*6291456, A1 + (long)b*6291456);
  }
  // 12) aligned = 1x1(permuted attn-out, proj_w) -> A0[0:12.58M]
  conv1x1<<<dim3(256,2), b256, 0, stream>>>(A1, 6291456L, proj_w, A0, 96L*HW, 96, 1);
  // 13-15) fhr qkv: three sequential 96-ch paths
  float* PRE  = A0 + 12582912;
  float* DW1  = A1 + 12582912;
  float* Q2NB = A1;
  // q2
  conv1x1<<<dim3(256,2), b256, 0, stream>>>(A0, 96L*HW, fqkv_w,        PRE, 96L*HW, 96, 0);
  dw3x3<<<dim3(256,96,2), b256, 0, stream>>>(PRE, fqkv_dw,        DW1, 96);
  l2n_sp<<<dim3(96,2), b1024, 0, stream>>>(DW1, Q2NB);
  // k2
  conv1x1<<<dim3(256,2), b256, 0, stream>>>(A0, 96L*HW, fqkv_w +  9216, PRE, 96L*HW, 96, 0);
  dw3x3<<<dim3(256,96,2), b256, 0, stream>>>(PRE, fqkv_dw +  864, DW1, 96);
  l2n_sp<<<dim3(96,2), b1024, 0, stream>>>(DW1, K2N);
  // v2 (raw dw output is the v2 output layout directly)
  conv1x1<<<dim3(256,2), b256, 0, stream>>>(A0, 96L*HW, fqkv_w + 18432, PRE, 96L*HW, 96, 0);
  dw3x3<<<dim3(256,96,2), b256, 0, stream>>>(PRE, fqkv_dw + 1728, V2, 96);
  // 16) a2 = softmax(q2n.k2n^T * fhr_temp)
  a2_kern<<<dim3(12,8,2), b256, 0, stream>>>(Q2NB, K2N, fhr_temp, A2S);
  // 17) o2pre = a2 @ v2 -> A0
  o2pre_kern<<<dim3(256,16), b256, 0, stream>>>(A2S, V2, A0);
  // 18) o2 = 1x1(o2pre, fproj_w) -> d_out
  conv1x1<<<dim3(256,2), b256, 0, stream>>>(A0, 96L*HW, fproj_w, O2, 96L*HW, 96, 0);
}

// Round 3
// 2728.756 us; speedup vs baseline: 1.9993x; 1.1303x over previous
//
#include <hip/hip_runtime.h>
#include <math.h>

#define HW 65536L

__device__ __forceinline__ int iabs_(int v) { return v < 0 ? -v : v; }

// ---------------- conv 1x1 (Cin=96), register-resident, no LDS ----------------
__global__ __launch_bounds__(256) void conv1x1(
    const float* __restrict__ in, long in_bstride,
    const float* __restrict__ w,
    float* __restrict__ out, long out_bstride,
    int Cout, int mode)
{
  const int t = threadIdx.x;
  const int p = blockIdx.x * 256 + t;
  const int b = blockIdx.y;
  float x[96];
  if (mode == 0) {
    const float* src = in + (long)b * in_bstride + p;
    #pragma unroll
    for (int c = 0; c < 96; c++) x[c] = src[(long)c * HW];
  } else {
    // input is attention output (B,4096,1536); spatial pixel p maps to
    // att[n][blk*96+ci], n=(y%64)*64+(x%64), blk=(y/64)*4+(x/64)
    const int py = p >> 8, px = p & 255;
    const float* src = in + (long)b * in_bstride
        + ((long)((py & 63)*64 + (px & 63)) * 16 + ((py >> 6)*4 + (px >> 6))) * 96;
    #pragma unroll
    for (int cb = 0; cb < 24; cb++) {
      float4 v = *(const float4*)&src[cb*4];
      x[cb*4+0] = v.x; x[cb*4+1] = v.y; x[cb*4+2] = v.z; x[cb*4+3] = v.w;
    }
  }
  float* dst = out + (long)b * out_bstride + p;
  const int ng = Cout >> 3;
  for (int g = 0; g < ng; g++) {
    const float* wg = w + g*8*96;
    float acc[8];
    #pragma unroll
    for (int j = 0; j < 8; j++) acc[j] = 0.f;
    #pragma unroll
    for (int k = 0; k < 96; k++) {
      float xv = x[k];
      #pragma unroll
      for (int j = 0; j < 8; j++) acc[j] = fmaf(wg[j*96 + k], xv, acc[j]);
    }
    #pragma unroll
    for (int j = 0; j < 8; j++) dst[(long)(g*8 + j) * HW] = acc[j];
  }
}

// ---------------- depthwise 3x3 pad 1 ----------------
__global__ __launch_bounds__(256) void dw3x3(
    const float* __restrict__ in, const float* __restrict__ w,
    float* __restrict__ out, int CH)
{
  const int t = threadIdx.x;
  const int p = blockIdx.x * 256 + t;
  const int ch = blockIdx.y, b = blockIdx.z;
  const int y = p >> 8, x = p & 255;
  const float* ip = in + (long)(b*CH + ch) * HW;
  const float* wp = w + ch*9;
  float acc = 0.f;
  #pragma unroll
  for (int dy = -1; dy <= 1; dy++) {
    int yy = y + dy;
    if (yy < 0 || yy > 255) continue;
    #pragma unroll
    for (int dx = -1; dx <= 1; dx++) {
      int xx = x + dx;
      if (xx < 0 || xx > 255) continue;
      acc = fmaf(ip[yy*256 + xx], wp[(dy+1)*3 + (dx+1)], acc);
    }
  }
  out[(long)(b*CH + ch) * HW + p] = acc;
}

// ------- depthwise 3x3 fused with v_s permutation (coalesced, LDS reorder) ----
// in: (B,96,256,256) pre-dw. out: v_s (B,4096,1536),
// v_s[b][n][blk*96+ci] = dw(in)[b][ci][(blk>>2)*64 + n/64][(blk&3)*64 + n%64]
// Block = (b, y, xb): computes all 96 ci at row y, cols xb*64..xb*64+63.
__global__ __launch_bounds__(256) void dw3x3_vs(
    const float* __restrict__ in, const float* __restrict__ w,
    float* __restrict__ vs)
{
  __shared__ float tile[96*65];
  const int t = threadIdx.x;
  const int gb = blockIdx.x;          // 0..1023 = y*4 + xb
  const int b = blockIdx.y;
  const int y = gb >> 2, xb = gb & 3;
  const int x0 = xb * 64;
  // compute phase: lanes sweep xl (coalesced taps)
  #pragma unroll
  for (int i = 0; i < 24; i++) {
    const int idx = i*256 + t;
    const int ci = idx >> 6, xl = idx & 63;
    const float* ip = in + ((long)b*96 + ci) * HW;
    const float* wp = w + ci*9;
    const int x = x0 + xl;
    float acc = 0.f;
    #pragma unroll
    for (int dy = -1; dy <= 1; dy++) {
      const int yy = y + dy;
      if (yy < 0 || yy > 255) continue;
      const float* rp = ip + yy*256;
      #pragma unroll
      for (int dx = -1; dx <= 1; dx++) {
        const int xx = x + dx;
        if (xx < 0 || xx > 255) continue;
        acc = fmaf(rp[xx], wp[(dy+1)*3 + (dx+1)], acc);
      }
    }
    tile[ci*65 + xl] = acc;
  }
  __syncthreads();
  // write phase: lanes sweep ci (coalesced permuted rows)
  const int blk = (y >> 6)*4 + xb;
  float* obase = vs + ((long)b*4096 + (long)(y & 63)*64) * 1536 + blk*96;
  #pragma unroll
  for (int i = 0; i < 24; i++) {
    const int idx = i*256 + t;
    const int nl = idx / 96, ci = idx % 96;
    obase[(long)nl*1536 + ci] = tile[ci*65 + nl];
  }
}

// ---------------- depthwise 4x4 stride 4 pad 1 (256->64) ----------------
__global__ __launch_bounds__(256) void dw4x4s4(
    const float* __restrict__ in, const float* __restrict__ w,
    float* __restrict__ out)
{
  const int t = threadIdx.x;
  const int op = blockIdx.x * 256 + t;
  const int ch = blockIdx.y, b = blockIdx.z;
  const int oy = op >> 6, ox = op & 63;
  const float* ip = in + (long)(b*192 + ch) * HW;
  const float* wp = w + ch*16;
  float acc = 0.f;
  #pragma unroll
  for (int ty = 0; ty < 4; ty++) {
    int iy = 4*oy + ty - 1;
    if (iy < 0 || iy > 255) continue;
    #pragma unroll
    for (int tx = 0; tx < 4; tx++) {
      int ix = 4*ox + tx - 1;
      if (ix < 0 || ix > 255) continue;
      acc = fmaf(ip[iy*256 + ix], wp[ty*4 + tx], acc);
    }
  }
  out[(long)(b*192 + ch) * 4096 + op] = acc;
}

// ---------------- l2 norm over 192 channels + transpose to (B,4096,192) ----
__global__ __launch_bounds__(256) void l2n192(
    const float* __restrict__ in, float* __restrict__ out)
{
  const int t = threadIdx.x;
  const int wid = t >> 6, lane = t & 63;
  const int gw = blockIdx.x * 4 + wid;      // 0..8191
  const int b = gw >> 12, n = gw & 4095;
  const float* ip = in + (long)b * 786432;  // 192*4096
  float v0 = ip[(long)(lane      ) * 4096 + n];
  float v1 = ip[(long)(lane +  64) * 4096 + n];
  float v2 = ip[(long)(lane + 128) * 4096 + n];
  float ss = v0*v0 + v1*v1 + v2*v2;
  #pragma unroll
  for (int s = 1; s < 64; s <<= 1) ss += __shfl_xor(ss, s, 64);
  float nrm = fmaxf(sqrtf(ss), 1e-12f);
  float* op = out + ((long)b*4096 + n) * 192;
  op[lane      ] = v0 / nrm;
  op[lane +  64] = v1 / nrm;
  op[lane + 128] = v2 / nrm;
}

// ---------------- attention QK^T (one batch): (4096,192)x(4096,192)^T -----
__global__ __launch_bounds__(256) void attn_qk(
    const float* __restrict__ qn, const float* __restrict__ kn,
    float* __restrict__ attn, const float* __restrict__ tp)
{
  __shared__ float qs[8*192];
  const int t = threadIdx.x;
  const int r0 = blockIdx.x * 8;
  for (int i = t; i < 8*192; i += 256) qs[i] = qn[(long)r0*192 + i];
  __syncthreads();
  const float temp = tp[0];
  for (int mc = 0; mc < 2; mc++) {
    const float* kb = kn + (long)(mc*2048 + t) * 192;
    float acc[64];
    #pragma unroll
    for (int i = 0; i < 64; i++) acc[i] = 0.f;
    for (int cb = 0; cb < 48; cb++) {
      float4 kv[8];
      #pragma unroll
      for (int jm = 0; jm < 8; jm++)
        kv[jm] = *(const float4*)&kb[(long)jm*256*192 + cb*4];
      #pragma unroll
      for (int r = 0; r < 8; r++) {
        float4 qv = *(const float4*)&qs[r*192 + cb*4];
        #pragma unroll
        for (int jm = 0; jm < 8; jm++) {
          acc[r*8+jm] = fmaf(qv.x, kv[jm].x, acc[r*8+jm]);
          acc[r*8+jm] = fmaf(qv.y, kv[jm].y, acc[r*8+jm]);
          acc[r*8+jm] = fmaf(qv.z, kv[jm].z, acc[r*8+jm]);
          acc[r*8+jm] = fmaf(qv.w, kv[jm].w, acc[r*8+jm]);
        }
      }
    }
    #pragma unroll
    for (int r = 0; r < 8; r++)
      #pragma unroll
      for (int jm = 0; jm < 8; jm++)
        attn[(long)(r0+r)*4096 + mc*2048 + jm*256 + t] = acc[r*8+jm] * temp;
  }
}

// ------- top-5 + local mask + softmax + sparse out (one batch, one row/blk) -
__global__ __launch_bounds__(256) void attn_out_k(
    const float* __restrict__ attn, const float* __restrict__ vs,
    float* __restrict__ outr)
{
  __shared__ float row[4096];
  __shared__ float top5[256*5];
  __shared__ int   lm[4096];
  __shared__ float lw[4096];
  __shared__ float redf[8];
  __shared__ int   scan[256];
  const int t = threadIdx.x;
  const int n = blockIdx.x;
  const float* ar = attn + (long)n * 4096;
  #pragma unroll
  for (int k = 0; k < 16; k++) row[k*256 + t] = ar[k*256 + t];
  __syncthreads();
  float t0=-INFINITY,t1=-INFINITY,t2=-INFINITY,t3=-INFINITY,t4=-INFINITY;
  #pragma unroll
  for (int k = 0; k < 16; k++) {
    float v = row[k*256 + t];
    if (v > t4) {
      if (v > t0)      { t4=t3; t3=t2; t2=t1; t1=t0; t0=v; }
      else if (v > t1) { t4=t3; t3=t2; t2=t1; t1=v; }
      else if (v > t2) { t4=t3; t3=t2; t2=v; }
      else if (v > t3) { t4=t3; t3=v; }
      else             { t4=v; }
    }
  }
  top5[t*5+0]=t0; top5[t*5+1]=t1; top5[t*5+2]=t2; top5[t*5+3]=t3; top5[t*5+4]=t4;
  __syncthreads();
  for (int s = 128; s >= 1; s >>= 1) {
    if (t < s) {
      float* A = &top5[t*5];
      const float* B = &top5[(t+s)*5];
      float m[5]; int i = 0, j = 0;
      #pragma unroll
      for (int k = 0; k < 5; k++) {
        float av = A[i], bv = B[j];
        if (av >= bv) { m[k] = av; i++; } else { m[k] = bv; j++; }
      }
      #pragma unroll
      for (int k = 0; k < 5; k++) A[k] = m[k];
    }
    __syncthreads();
  }
  const float kth = top5[4];
  const int y = n >> 6, x = n & 63;
  int myc = 0;
  float wmax = -INFINITY;
  #pragma unroll
  for (int k = 0; k < 16; k++) {
    int m = k*256 + t;
    float a = row[m];
    int c = ((a >= kth) ? 1 : 0) +
            (((iabs_(y - (m >> 6)) + iabs_(x - (m & 63))) <= 4) ? 1 : 0);
    float wv = a * (float)c;
    if (wv != 0.0f) { myc++; wmax = fmaxf(wmax, wv); }
  }
  scan[t] = myc;
  __syncthreads();
  for (int s = 1; s < 256; s <<= 1) {
    int v = (t >= s) ? scan[t-s] : 0;
    __syncthreads();
    scan[t] += v;
    __syncthreads();
  }
  const int base = scan[t] - myc;
  const int cnt = scan[255];
  {
    int idx = base;
    #pragma unroll
    for (int k = 0; k < 16; k++) {
      int m = k*256 + t;
      float a = row[m];
      int c = ((a >= kth) ? 1 : 0) +
              (((iabs_(y - (m >> 6)) + iabs_(x - (m & 63))) <= 4) ? 1 : 0);
      float wv = a * (float)c;
      if (wv != 0.0f) { lm[idx] = m; lw[idx] = wv; idx++; }
    }
  }
  #pragma unroll
  for (int s = 1; s < 64; s <<= 1) wmax = fmaxf(wmax, __shfl_xor(wmax, s, 64));
  if ((t & 63) == 0) redf[t >> 6] = wmax;
  __syncthreads();
  const float gmax = fmaxf(fmaxf(redf[0], redf[1]), fmaxf(redf[2], redf[3]));
  __syncthreads();
  float ps = 0.f;
  for (int i = t; i < cnt; i += 256) ps += expf(lw[i] - gmax);
  #pragma unroll
  for (int s = 1; s < 64; s <<= 1) ps += __shfl_xor(ps, s, 64);
  if ((t & 63) == 0) redf[4 + (t >> 6)] = ps;
  __syncthreads();
  const float S = redf[4] + redf[5] + redf[6] + redf[7];
  const float invS = 1.0f / S;
  float a0=0,a1=0,a2=0,a3=0,a4=0,a5=0;
  for (int e = 0; e < cnt; e++) {
    float se = expf(lw[e] - gmax) * invS;
    const float* vr = vs + (long)lm[e] * 1536;
    a0 = fmaf(se, vr[          t], a0);
    a1 = fmaf(se, vr[ 256 + t], a1);
    a2 = fmaf(se, vr[ 512 + t], a2);
    a3 = fmaf(se, vr[ 768 + t], a3);
    a4 = fmaf(se, vr[1024 + t], a4);
    a5 = fmaf(se, vr[1280 + t], a5);
  }
  float* orow = outr + (long)n * 1536;
  orow[          t] = a0;
  orow[ 256 + t] = a1;
  orow[ 512 + t] = a2;
  orow[ 768 + t] = a3;
  orow[1024 + t] = a4;
  orow[1280 + t] = a5;
}

// ---------------- per-channel l2 norm over 65536 (fhr q2/k2) ----------------
__global__ __launch_bounds__(1024) void l2n_sp(
    const float* __restrict__ in, float* __restrict__ out)
{
  const int ch = blockIdx.x, b = blockIdx.y, t = threadIdx.x;
  const float* ip = in + ((long)b*96 + ch) * HW;
  float ss = 0.f;
  for (int i = t; i < 65536; i += 1024) { float v = ip[i]; ss = fmaf(v, v, ss); }
  __shared__ float red[16];
  #pragma unroll
  for (int s = 1; s < 64; s <<= 1) ss += __shfl_xor(ss, s, 64);
  if ((t & 63) == 0) red[t >> 6] = ss;
  __syncthreads();
  if (t == 0) {
    float s2 = 0.f;
    for (int i = 0; i < 16; i++) s2 += red[i];
    red[0] = fmaxf(sqrtf(s2), 1e-12f);
  }
  __syncthreads();
  const float nrm = red[0];
  float* op = out + ((long)b*96 + ch) * HW;
  for (int i = t; i < 65536; i += 1024) op[i] = ip[i] / nrm;
}

// ---------------- a2 = softmax(q2n . k2n^T * temp) per (b,h,c) --------------
__global__ __launch_bounds__(256) void a2_kern(
    const float* __restrict__ q2n, const float* __restrict__ k2n,
    const float* __restrict__ temp, float* __restrict__ a2s)
{
  const int c = blockIdx.x, h = blockIdx.y, b = blockIdx.z, t = threadIdx.x;
  const float* q = q2n + ((long)b*96 + h*12 + c) * HW;
  const float* k = k2n + ((long)b*96 + h*12) * HW;
  float p[12];
  #pragma unroll
  for (int d = 0; d < 12; d++) p[d] = 0.f;
  for (int i = t; i < 65536; i += 256) {
    float qv = q[i];
    #pragma unroll
    for (int d = 0; d < 12; d++) p[d] = fmaf(qv, k[(long)d*HW + i], p[d]);
  }
  __shared__ float red[12*256];
  #pragma unroll
  for (int d = 0; d < 12; d++) red[d*256 + t] = p[d];
  __syncthreads();
  for (int s = 128; s >= 1; s >>= 1) {
    if (t < s) {
      #pragma unroll
      for (int d = 0; d < 12; d++) red[d*256 + t] += red[d*256 + t + s];
    }
    __syncthreads();
  }
  if (t == 0) {
    float tv = temp[h];
    float a[12], mx = -INFINITY;
    #pragma unroll
    for (int d = 0; d < 12; d++) { a[d] = red[d*256] * tv; mx = fmaxf(mx, a[d]); }
    float sum = 0.f;
    #pragma unroll
    for (int d = 0; d < 12; d++) { a[d] = expf(a[d] - mx); sum += a[d]; }
    float inv = 1.0f / sum;
    #pragma unroll
    for (int d = 0; d < 12; d++)
      a2s[(((long)b*8 + h)*12 + c)*12 + d] = a[d] * inv;
  }
}

// ---------------- o2pre = a2 @ v2 ----------------
__global__ __launch_bounds__(256) void o2pre_kern(
    const float* __restrict__ a2s, const float* __restrict__ v2,
    float* __restrict__ o2p)
{
  const int t = threadIdx.x;
  const int n = blockIdx.x * 256 + t;
  const int bh = blockIdx.y, b = bh >> 3, h = bh & 7;
  const float* a = a2s + (long)bh * 144;
  const float* vb = v2 + ((long)b*96 + h*12) * HW;
  float vv[12];
  #pragma unroll
  for (int d = 0; d < 12; d++) vv[d] = vb[(long)d*HW + n];
  float* ob = o2p + ((long)b*96 + h*12) * HW;
  #pragma unroll
  for (int c = 0; c < 12; c++) {
    float s = 0.f;
    #pragma unroll
    for (int d = 0; d < 12; d++) s = fmaf(a[c*12 + d], vv[d], s);
    ob[(long)c*HW + n] = s;
  }
}

extern "C" void kernel_launch(void* const* d_in, const int* in_sizes, int n_in,
                              void* d_out, int out_size, void* d_ws, size_t ws_size,
                              hipStream_t stream) {
  const float* x        = (const float*)d_in[0];
  const float* qk_w     = (const float*)d_in[1];
  const float* qk_dw    = (const float*)d_in[2];
  const float* v_w      = (const float*)d_in[3];
  const float* v_dw     = (const float*)d_in[4];
  const float* k2_w     = (const float*)d_in[5];
  const float* k2_dw    = (const float*)d_in[6];
  const float* q2_w     = (const float*)d_in[7];
  const float* q2_dw    = (const float*)d_in[8];
  const float* proj_w   = (const float*)d_in[9];
  const float* sab_temp = (const float*)d_in[10];
  const float* fqkv_w   = (const float*)d_in[11];
  const float* fqkv_dw  = (const float*)d_in[12];
  const float* fproj_w  = (const float*)d_in[13];
  const float* fhr_temp = (const float*)d_in[14];
  float* out = (float*)d_out;
  float* ws  = (float*)d_ws;

  // d_out regions (floats)
  float* O2  = out;               // (2,96,256,256)
  float* KS  = out + 12582912;    // (2,1,1,4096,192)  = normalized k
  float* VS  = out + 14155776;    // (2,1,1,4096,1536) = permuted v
  float* K2N = out + 26738688;    // (2,8,12,65536)    = normalized k2
  float* V2  = out + 39321600;    // (2,8,12,65536)    = raw v2

  // ws arena (floats)
  float* A0  = ws;                // 25165824
  float* A1  = ws + 25165824;     // 25165824
  float* QD  = ws + 50331648;     // 1572864
  float* KD  = ws + 51904512;     // 1572864
  float* QN  = ws + 53477376;     // 1572864
  float* A2S = ws + 55050240;     // 2304

  dim3 b256(256), b1024(1024);

  // 1) y1_qk = 1x1(x, qk_w) -> A0 (2,192,HW)
  conv1x1<<<dim3(256,2), b256, 0, stream>>>(x, 96L*HW, qk_w, A0, 192L*HW, 192, 0);
  // 2) qk = dw3x3(y1_qk) -> A1 (2,192,HW); q=ch[0:96), k=ch[96:192)
  dw3x3<<<dim3(256,192,2), b256, 0, stream>>>(A0, qk_dw, A1, 192);
  // 3) y1_v = 1x1(x, v_w) -> A0 (2,96,HW)
  conv1x1<<<dim3(256,2), b256, 0, stream>>>(x, 96L*HW, v_w, A0, 96L*HW, 96, 0);
  // 4) v_s = permute(dw3x3(y1_v)) -> d_out
  dw3x3_vs<<<dim3(1024,2), b256, 0, stream>>>(A0, v_dw, VS);
  // 5) q2pre = 1x1(q, q2_w) -> A0 (2,192,HW)
  conv1x1<<<dim3(256,2), b256, 0, stream>>>(A1, 192L*HW, q2_w, A0, 192L*HW, 192, 0);
  // 6) qd = dw4x4s4(q2pre)
  dw4x4s4<<<dim3(16,192,2), b256, 0, stream>>>(A0, q2_dw, QD);
  // 7) k2pre = 1x1(k, k2_w) -> A0
  conv1x1<<<dim3(256,2), b256, 0, stream>>>(A1 + 96L*HW, 192L*HW, k2_w, A0, 192L*HW, 192, 0);
  // 8) kd = dw4x4s4(k2pre)
  dw4x4s4<<<dim3(16,192,2), b256, 0, stream>>>(A0, k2_dw, KD);
  // 9/10) l2norm + transpose -> qn (ws), kn (d_out k_s)
  l2n192<<<dim3(2048), b256, 0, stream>>>(QD, QN);
  l2n192<<<dim3(2048), b256, 0, stream>>>(KD, KS);
  // 11) attention, per batch (attn materialized in A0, 4096x4096)
  for (int b = 0; b < 2; b++) {
    attn_qk<<<dim3(512), b256, 0, stream>>>(
        QN + (long)b*786432, KS + (long)b*786432, A0, sab_temp);
    attn_out_k<<<dim3(4096), b256, 0, stream>>>(
        A0, VS + (long)b*6291456, A1 + (long)b*6291456);
  }
  // 12) aligned = 1x1(permuted attn-out, proj_w) -> A0[0:12.58M]
  conv1x1<<<dim3(256,2), b256, 0, stream>>>(A1, 6291456L, proj_w, A0, 96L*HW, 96, 1);
  // 13-15) fhr qkv: three sequential 96-ch paths
  float* PRE  = A0 + 12582912;
  float* DW1  = A1 + 12582912;
  float* Q2NB = A1;
  // q2
  conv1x1<<<dim3(256,2), b256, 0, stream>>>(A0, 96L*HW, fqkv_w,        PRE, 96L*HW, 96, 0);
  dw3x3<<<dim3(256,96,2), b256, 0, stream>>>(PRE, fqkv_dw,        DW1, 96);
  l2n_sp<<<dim3(96,2), b1024, 0, stream>>>(DW1, Q2NB);
  // k2
  conv1x1<<<dim3(256,2), b256, 0, stream>>>(A0, 96L*HW, fqkv_w +  9216, PRE, 96L*HW, 96, 0);
  dw3x3<<<dim3(256,96,2), b256, 0, stream>>>(PRE, fqkv_dw +  864, DW1, 96);
  l2n_sp<<<dim3(96,2), b1024, 0, stream>>>(DW1, K2N);
  // v2 (raw dw output is the v2 output layout directly)
  conv1x1<<<dim3(256,2), b256, 0, stream>>>(A0, 96L*HW, fqkv_w + 18432, PRE, 96L*HW, 96, 0);
  dw3x3<<<dim3(256,96,2), b256, 0, stream>>>(PRE, fqkv_dw + 1728, V2, 96);
  // 16) a2 = softmax(q2n.k2n^T * fhr_temp)
  a2_kern<<<dim3(12,8,2), b256, 0, stream>>>(Q2NB, K2N, fhr_temp, A2S);
  // 17) o2pre = a2 @ v2 -> A0
  o2pre_kern<<<dim3(256,16), b256, 0, stream>>>(A2S, V2, A0);
  // 18) o2 = 1x1(o2pre, fproj_w) -> d_out
  conv1x1<<<dim3(256,2), b256, 0, stream>>>(A0, 96L*HW, fproj_w, O2, 96L*HW, 96, 0);
}

// Round 4
// 2000.653 us; speedup vs baseline: 2.7269x; 1.3639x over previous
//
#include <hip/hip_runtime.h>
#include <hip/hip_bf16.h>
#include <math.h>

#define HW 65536L

typedef __attribute__((ext_vector_type(8))) short bf16x8;
typedef __attribute__((ext_vector_type(4))) float f32x4;

__device__ __forceinline__ int iabs_(int v) { return v < 0 ? -v : v; }

// ---------------- conv 1x1 (Cin=96), register-resident, no LDS ----------------
__global__ __launch_bounds__(256) void conv1x1(
    const float* __restrict__ in, long in_bstride,
    const float* __restrict__ w,
    float* __restrict__ out, long out_bstride,
    int Cout, int mode)
{
  const int t = threadIdx.x;
  const int p = blockIdx.x * 256 + t;
  const int b = blockIdx.y;
  float x[96];
  if (mode == 0) {
    const float* src = in + (long)b * in_bstride + p;
    #pragma unroll
    for (int c = 0; c < 96; c++) x[c] = src[(long)c * HW];
  } else {
    // input is attention output (B,4096,1536); spatial pixel p maps to
    // att[n][blk*96+ci], n=(y%64)*64+(x%64), blk=(y/64)*4+(x/64)
    const int py = p >> 8, px = p & 255;
    const float* src = in + (long)b * in_bstride
        + ((long)((py & 63)*64 + (px & 63)) * 16 + ((py >> 6)*4 + (px >> 6))) * 96;
    #pragma unroll
    for (int cb = 0; cb < 24; cb++) {
      float4 v = *(const float4*)&src[cb*4];
      x[cb*4+0] = v.x; x[cb*4+1] = v.y; x[cb*4+2] = v.z; x[cb*4+3] = v.w;
    }
  }
  float* dst = out + (long)b * out_bstride + p;
  const int ng = Cout >> 3;
  for (int g = 0; g < ng; g++) {
    const float* wg = w + g*8*96;
    float acc[8];
    #pragma unroll
    for (int j = 0; j < 8; j++) acc[j] = 0.f;
    #pragma unroll
    for (int k = 0; k < 96; k++) {
      float xv = x[k];
      #pragma unroll
      for (int j = 0; j < 8; j++) acc[j] = fmaf(wg[j*96 + k], xv, acc[j]);
    }
    #pragma unroll
    for (int j = 0; j < 8; j++) dst[(long)(g*8 + j) * HW] = acc[j];
  }
}

// ---------------- depthwise 3x3 pad 1 ----------------
__global__ __launch_bounds__(256) void dw3x3(
    const float* __restrict__ in, const float* __restrict__ w,
    float* __restrict__ out, int CH)
{
  const int t = threadIdx.x;
  const int p = blockIdx.x * 256 + t;
  const int ch = blockIdx.y, b = blockIdx.z;
  const int y = p >> 8, x = p & 255;
  const float* ip = in + (long)(b*CH + ch) * HW;
  const float* wp = w + ch*9;
  float acc = 0.f;
  #pragma unroll
  for (int dy = -1; dy <= 1; dy++) {
    int yy = y + dy;
    if (yy < 0 || yy > 255) continue;
    #pragma unroll
    for (int dx = -1; dx <= 1; dx++) {
      int xx = x + dx;
      if (xx < 0 || xx > 255) continue;
      acc = fmaf(ip[yy*256 + xx], wp[(dy+1)*3 + (dx+1)], acc);
    }
  }
  out[(long)(b*CH + ch) * HW + p] = acc;
}

// ------- depthwise 3x3 fused with v_s permutation (coalesced, LDS reorder) ----
__global__ __launch_bounds__(256) void dw3x3_vs(
    const float* __restrict__ in, const float* __restrict__ w,
    float* __restrict__ vs)
{
  __shared__ float tile[96*65];
  const int t = threadIdx.x;
  const int gb = blockIdx.x;          // 0..1023 = y*4 + xb
  const int b = blockIdx.y;
  const int y = gb >> 2, xb = gb & 3;
  const int x0 = xb * 64;
  #pragma unroll
  for (int i = 0; i < 24; i++) {
    const int idx = i*256 + t;
    const int ci = idx >> 6, xl = idx & 63;
    const float* ip = in + ((long)b*96 + ci) * HW;
    const float* wp = w + ci*9;
    const int x = x0 + xl;
    float acc = 0.f;
    #pragma unroll
    for (int dy = -1; dy <= 1; dy++) {
      const int yy = y + dy;
      if (yy < 0 || yy > 255) continue;
      const float* rp = ip + yy*256;
      #pragma unroll
      for (int dx = -1; dx <= 1; dx++) {
        const int xx = x + dx;
        if (xx < 0 || xx > 255) continue;
        acc = fmaf(rp[xx], wp[(dy+1)*3 + (dx+1)], acc);
      }
    }
    tile[ci*65 + xl] = acc;
  }
  __syncthreads();
  const int blk = (y >> 6)*4 + xb;
  float* obase = vs + ((long)b*4096 + (long)(y & 63)*64) * 1536 + blk*96;
  #pragma unroll
  for (int i = 0; i < 24; i++) {
    const int idx = i*256 + t;
    const int nl = idx / 96, ci = idx % 96;
    obase[(long)nl*1536 + ci] = tile[ci*65 + nl];
  }
}

// ---------------- depthwise 4x4 stride 4 pad 1 (256->64) ----------------
__global__ __launch_bounds__(256) void dw4x4s4(
    const float* __restrict__ in, const float* __restrict__ w,
    float* __restrict__ out)
{
  const int t = threadIdx.x;
  const int op = blockIdx.x * 256 + t;
  const int ch = blockIdx.y, b = blockIdx.z;
  const int oy = op >> 6, ox = op & 63;
  const float* ip = in + (long)(b*192 + ch) * HW;
  const float* wp = w + ch*16;
  float acc = 0.f;
  #pragma unroll
  for (int ty = 0; ty < 4; ty++) {
    int iy = 4*oy + ty - 1;
    if (iy < 0 || iy > 255) continue;
    #pragma unroll
    for (int tx = 0; tx < 4; tx++) {
      int ix = 4*ox + tx - 1;
      if (ix < 0 || ix > 255) continue;
      acc = fmaf(ip[iy*256 + ix], wp[ty*4 + tx], acc);
    }
  }
  out[(long)(b*192 + ch) * 4096 + op] = acc;
}

// ---------------- l2 norm over 192 channels + transpose to (B,4096,192) ----
__global__ __launch_bounds__(256) void l2n192(
    const float* __restrict__ in, float* __restrict__ out)
{
  const int t = threadIdx.x;
  const int wid = t >> 6, lane = t & 63;
  const int gw = blockIdx.x * 4 + wid;      // 0..8191
  const int b = gw >> 12, n = gw & 4095;
  const float* ip = in + (long)b * 786432;  // 192*4096
  float v0 = ip[(long)(lane      ) * 4096 + n];
  float v1 = ip[(long)(lane +  64) * 4096 + n];
  float v2 = ip[(long)(lane + 128) * 4096 + n];
  float ss = v0*v0 + v1*v1 + v2*v2;
  #pragma unroll
  for (int s = 1; s < 64; s <<= 1) ss += __shfl_xor(ss, s, 64);
  float nrm = fmaxf(sqrtf(ss), 1e-12f);
  float* op = out + ((long)b*4096 + n) * 192;
  op[lane      ] = v0 / nrm;
  op[lane +  64] = v1 / nrm;
  op[lane + 128] = v2 / nrm;
}

// ---------------- split fp32 -> (hi,lo) bf16 planes: (4096,192) -> (4096,384) -
__global__ __launch_bounds__(256) void bf16split(
    const float* __restrict__ in, unsigned short* __restrict__ outp)
{
  const int i = blockIdx.x * 256 + threadIdx.x;   // 0..786431
  const int n = i / 192, k = i % 192;
  float f = in[i];
  __hip_bfloat16 h = __float2bfloat16(f);
  float hf = __bfloat162float(h);
  __hip_bfloat16 l = __float2bfloat16(f - hf);
  outp[(long)n*384 + k]       = *(unsigned short*)&h;
  outp[(long)n*384 + 192 + k] = *(unsigned short*)&l;
}

// ---------------- attention QK^T via split-bf16 MFMA (one batch) ------------
// attn[n][m] = (Q[n] . K[m]) * temp; Q,K as (4096,384) hi/lo bf16 planes.
// Block: 128 Q-rows x 128 K-rows; 4 waves, each 64x64 (4x4 mfma 16x16x32).
#define LDSROW 40   // ushorts per staged row (32 data + 8 pad) = 80 B
__global__ __launch_bounds__(256) void attn_qk_mfma(
    const unsigned short* __restrict__ Qsp, const unsigned short* __restrict__ Ksp,
    float* __restrict__ attn, const float* __restrict__ tp)
{
  __shared__ unsigned short qs[256*LDSROW];   // [hl*128+row][LDSROW]
  __shared__ unsigned short ks[256*LDSROW];
  const int t = threadIdx.x;
  const int lane = t & 63, w = t >> 6;
  const int n0 = blockIdx.x * 128;   // Q rows
  const int m0 = blockIdx.y * 128;   // K rows
  const int wr = (w >> 1) * 64, wc = (w & 1) * 64;
  f32x4 acc[4][4] = {};
  // staging: thread t handles one 64B row-segment (hi or lo) of Q and K
  const int srow = t & 127;
  const int shl  = t >> 7;           // 0 = hi plane, 1 = lo plane
  const unsigned short* qsrc = Qsp + (long)(n0 + srow) * 384 + shl * 192;
  const unsigned short* ksrc = Ksp + (long)(m0 + srow) * 384 + shl * 192;
  unsigned short* qdst = qs + (shl*128 + srow) * LDSROW;
  unsigned short* kdst = ks + (shl*128 + srow) * LDSROW;
  const int fr = lane & 15;          // fragment row/col within 16
  const int fk = lane >> 4;          // k-subblock (8 bf16 each)
  for (int s = 0; s < 6; s++) {
    __syncthreads();
    #pragma unroll
    for (int j = 0; j < 4; j++) {
      *(bf16x8*)(qdst + j*8) = *(const bf16x8*)(qsrc + s*32 + j*8);
      *(bf16x8*)(kdst + j*8) = *(const bf16x8*)(ksrc + s*32 + j*8);
    }
    __syncthreads();
    bf16x8 ah[4], al[4], bh[4], bl[4];
    #pragma unroll
    for (int i = 0; i < 4; i++) {
      ah[i] = *(const bf16x8*)(qs + (      wr + i*16 + fr) * LDSROW + fk*8);
      al[i] = *(const bf16x8*)(qs + (128 + wr + i*16 + fr) * LDSROW + fk*8);
      bh[i] = *(const bf16x8*)(ks + (      wc + i*16 + fr) * LDSROW + fk*8);
      bl[i] = *(const bf16x8*)(ks + (128 + wc + i*16 + fr) * LDSROW + fk*8);
    }
    #pragma unroll
    for (int i = 0; i < 4; i++)
      #pragma unroll
      for (int j = 0; j < 4; j++) {
        acc[i][j] = __builtin_amdgcn_mfma_f32_16x16x32_bf16(ah[i], bh[j], acc[i][j], 0, 0, 0);
        acc[i][j] = __builtin_amdgcn_mfma_f32_16x16x32_bf16(ah[i], bl[j], acc[i][j], 0, 0, 0);
        acc[i][j] = __builtin_amdgcn_mfma_f32_16x16x32_bf16(al[i], bh[j], acc[i][j], 0, 0, 0);
      }
  }
  const float temp = tp[0];
  #pragma unroll
  for (int i = 0; i < 4; i++)
    #pragma unroll
    for (int j = 0; j < 4; j++)
      #pragma unroll
      for (int r = 0; r < 4; r++) {
        const int nn = n0 + wr + i*16 + (lane >> 4)*4 + r;  // Q row (M)
        const int mm = m0 + wc + j*16 + (lane & 15);        // K row (N)
        attn[(long)nn*4096 + mm] = acc[i][j][r] * temp;
      }
}

// ------- top-5 + local mask + softmax + sparse out (one batch, one row/blk) -
__global__ __launch_bounds__(256) void attn_out_k(
    const float* __restrict__ attn, const float* __restrict__ vs,
    float* __restrict__ outr)
{
  __shared__ float row[4096];
  __shared__ float top5[256*5];
  __shared__ int   lm[4096];
  __shared__ float lw[4096];
  __shared__ float redf[8];
  __shared__ int   scan[256];
  const int t = threadIdx.x;
  const int n = blockIdx.x;
  const float* ar = attn + (long)n * 4096;
  #pragma unroll
  for (int k = 0; k < 16; k++) row[k*256 + t] = ar[k*256 + t];
  __syncthreads();
  float t0=-INFINITY,t1=-INFINITY,t2=-INFINITY,t3=-INFINITY,t4=-INFINITY;
  #pragma unroll
  for (int k = 0; k < 16; k++) {
    float v = row[k*256 + t];
    if (v > t4) {
      if (v > t0)      { t4=t3; t3=t2; t2=t1; t1=t0; t0=v; }
      else if (v > t1) { t4=t3; t3=t2; t2=t1; t1=v; }
      else if (v > t2) { t4=t3; t3=t2; t2=v; }
      else if (v > t3) { t4=t3; t3=v; }
      else             { t4=v; }
    }
  }
  top5[t*5+0]=t0; top5[t*5+1]=t1; top5[t*5+2]=t2; top5[t*5+3]=t3; top5[t*5+4]=t4;
  __syncthreads();
  for (int s = 128; s >= 1; s >>= 1) {
    if (t < s) {
      float* A = &top5[t*5];
      const float* B = &top5[(t+s)*5];
      float m[5]; int i = 0, j = 0;
      #pragma unroll
      for (int k = 0; k < 5; k++) {
        float av = A[i], bv = B[j];
        if (av >= bv) { m[k] = av; i++; } else { m[k] = bv; j++; }
      }
      #pragma unroll
      for (int k = 0; k < 5; k++) A[k] = m[k];
    }
    __syncthreads();
  }
  const float kth = top5[4];
  const int y = n >> 6, x = n & 63;
  int myc = 0;
  float wmax = -INFINITY;
  #pragma unroll
  for (int k = 0; k < 16; k++) {
    int m = k*256 + t;
    float a = row[m];
    int c = ((a >= kth) ? 1 : 0) +
            (((iabs_(y - (m >> 6)) + iabs_(x - (m & 63))) <= 4) ? 1 : 0);
    float wv = a * (float)c;
    if (wv != 0.0f) { myc++; wmax = fmaxf(wmax, wv); }
  }
  scan[t] = myc;
  __syncthreads();
  for (int s = 1; s < 256; s <<= 1) {
    int v = (t >= s) ? scan[t-s] : 0;
    __syncthreads();
    scan[t] += v;
    __syncthreads();
  }
  const int base = scan[t] - myc;
  const int cnt = scan[255];
  {
    int idx = base;
    #pragma unroll
    for (int k = 0; k < 16; k++) {
      int m = k*256 + t;
      float a = row[m];
      int c = ((a >= kth) ? 1 : 0) +
              (((iabs_(y - (m >> 6)) + iabs_(x - (m & 63))) <= 4) ? 1 : 0);
      float wv = a * (float)c;
      if (wv != 0.0f) { lm[idx] = m; lw[idx] = wv; idx++; }
    }
  }
  #pragma unroll
  for (int s = 1; s < 64; s <<= 1) wmax = fmaxf(wmax, __shfl_xor(wmax, s, 64));
  if ((t & 63) == 0) redf[t >> 6] = wmax;
  __syncthreads();
  const float gmax = fmaxf(fmaxf(redf[0], redf[1]), fmaxf(redf[2], redf[3]));
  __syncthreads();
  float ps = 0.f;
  for (int i = t; i < cnt; i += 256) ps += expf(lw[i] - gmax);
  #pragma unroll
  for (int s = 1; s < 64; s <<= 1) ps += __shfl_xor(ps, s, 64);
  if ((t & 63) == 0) redf[4 + (t >> 6)] = ps;
  __syncthreads();
  const float S = redf[4] + redf[5] + redf[6] + redf[7];
  const float invS = 1.0f / S;
  float a0=0,a1=0,a2=0,a3=0,a4=0,a5=0;
  for (int e = 0; e < cnt; e++) {
    float se = expf(lw[e] - gmax) * invS;
    const float* vr = vs + (long)lm[e] * 1536;
    a0 = fmaf(se, vr[          t], a0);
    a1 = fmaf(se, vr[ 256 + t], a1);
    a2 = fmaf(se, vr[ 512 + t], a2);
    a3 = fmaf(se, vr[ 768 + t], a3);
    a4 = fmaf(se, vr[1024 + t], a4);
    a5 = fmaf(se, vr[1280 + t], a5);
  }
  float* orow = outr + (long)n * 1536;
  orow[          t] = a0;
  orow[ 256 + t] = a1;
  orow[ 512 + t] = a2;
  orow[ 768 + t] = a3;
  orow[1024 + t] = a4;
  orow[1280 + t] = a5;
}

// ---------------- per-channel l2 norm over 65536 (fhr q2/k2) ----------------
__global__ __launch_bounds__(1024) void l2n_sp(
    const float* __restrict__ in, float* __restrict__ out)
{
  const int ch = blockIdx.x, b = blockIdx.y, t = threadIdx.x;
  const float* ip = in + ((long)b*96 + ch) * HW;
  float ss = 0.f;
  for (int i = t; i < 65536; i += 1024) { float v = ip[i]; ss = fmaf(v, v, ss); }
  __shared__ float red[16];
  #pragma unroll
  for (int s = 1; s < 64; s <<= 1) ss += __shfl_xor(ss, s, 64);
  if ((t & 63) == 0) red[t >> 6] = ss;
  __syncthreads();
  if (t == 0) {
    float s2 = 0.f;
    for (int i = 0; i < 16; i++) s2 += red[i];
    red[0] = fmaxf(sqrtf(s2), 1e-12f);
  }
  __syncthreads();
  const float nrm = red[0];
  float* op = out + ((long)b*96 + ch) * HW;
  for (int i = t; i < 65536; i += 1024) op[i] = ip[i] / nrm;
}

// ---------------- a2 = softmax(q2n . k2n^T * temp) per (b,h,c) --------------
__global__ __launch_bounds__(256) void a2_kern(
    const float* __restrict__ q2n, const float* __restrict__ k2n,
    const float* __restrict__ temp, float* __restrict__ a2s)
{
  const int c = blockIdx.x, h = blockIdx.y, b = blockIdx.z, t = threadIdx.x;
  const float* q = q2n + ((long)b*96 + h*12 + c) * HW;
  const float* k = k2n + ((long)b*96 + h*12) * HW;
  float p[12];
  #pragma unroll
  for (int d = 0; d < 12; d++) p[d] = 0.f;
  for (int i = t; i < 65536; i += 256) {
    float qv = q[i];
    #pragma unroll
    for (int d = 0; d < 12; d++) p[d] = fmaf(qv, k[(long)d*HW + i], p[d]);
  }
  __shared__ float red[12*256];
  #pragma unroll
  for (int d = 0; d < 12; d++) red[d*256 + t] = p[d];
  __syncthreads();
  for (int s = 128; s >= 1; s >>= 1) {
    if (t < s) {
      #pragma unroll
      for (int d = 0; d < 12; d++) red[d*256 + t] += red[d*256 + t + s];
    }
    __syncthreads();
  }
  if (t == 0) {
    float tv = temp[h];
    float a[12], mx = -INFINITY;
    #pragma unroll
    for (int d = 0; d < 12; d++) { a[d] = red[d*256] * tv; mx = fmaxf(mx, a[d]); }
    float sum = 0.f;
    #pragma unroll
    for (int d = 0; d < 12; d++) { a[d] = expf(a[d] - mx); sum += a[d]; }
    float inv = 1.0f / sum;
    #pragma unroll
    for (int d = 0; d < 12; d++)
      a2s[(((long)b*8 + h)*12 + c)*12 + d] = a[d] * inv;
  }
}

// ---------------- o2pre = a2 @ v2 ----------------
__global__ __launch_bounds__(256) void o2pre_kern(
    const float* __restrict__ a2s, const float* __restrict__ v2,
    float* __restrict__ o2p)
{
  const int t = threadIdx.x;
  const int n = blockIdx.x * 256 + t;
  const int bh = blockIdx.y, b = bh >> 3, h = bh & 7;
  const float* a = a2s + (long)bh * 144;
  const float* vb = v2 + ((long)b*96 + h*12) * HW;
  float vv[12];
  #pragma unroll
  for (int d = 0; d < 12; d++) vv[d] = vb[(long)d*HW + n];
  float* ob = o2p + ((long)b*96 + h*12) * HW;
  #pragma unroll
  for (int c = 0; c < 12; c++) {
    float s = 0.f;
    #pragma unroll
    for (int d = 0; d < 12; d++) s = fmaf(a[c*12 + d], vv[d], s);
    ob[(long)c*HW + n] = s;
  }
}

extern "C" void kernel_launch(void* const* d_in, const int* in_sizes, int n_in,
                              void* d_out, int out_size, void* d_ws, size_t ws_size,
                              hipStream_t stream) {
  const float* x        = (const float*)d_in[0];
  const float* qk_w     = (const float*)d_in[1];
  const float* qk_dw    = (const float*)d_in[2];
  const float* v_w      = (const float*)d_in[3];
  const float* v_dw     = (const float*)d_in[4];
  const float* k2_w     = (const float*)d_in[5];
  const float* k2_dw    = (const float*)d_in[6];
  const float* q2_w     = (const float*)d_in[7];
  const float* q2_dw    = (const float*)d_in[8];
  const float* proj_w   = (const float*)d_in[9];
  const float* sab_temp = (const float*)d_in[10];
  const float* fqkv_w   = (const float*)d_in[11];
  const float* fqkv_dw  = (const float*)d_in[12];
  const float* fproj_w  = (const float*)d_in[13];
  const float* fhr_temp = (const float*)d_in[14];
  float* out = (float*)d_out;
  float* ws  = (float*)d_ws;

  // d_out regions (floats)
  float* O2  = out;               // (2,96,256,256)
  float* KS  = out + 12582912;    // (2,1,1,4096,192)  = normalized k
  float* VS  = out + 14155776;    // (2,1,1,4096,1536) = permuted v
  float* K2N = out + 26738688;    // (2,8,12,65536)    = normalized k2
  float* V2  = out + 39321600;    // (2,8,12,65536)    = raw v2

  // ws arena (floats)
  float* A0  = ws;                // 25165824 (attn uses first 16777216)
  float* A1  = ws + 25165824;     // 25165824
  float* QD  = ws + 50331648;     // 1572864
  float* KD  = ws + 51904512;     // 1572864
  float* QN  = ws + 53477376;     // 1572864
  float* A2S = ws + 55050240;     // 2304
  // split-bf16 planes live in A0's tail (beyond the 16.7M-float attn buffer)
  unsigned short* QSP = (unsigned short*)(A0 + 16777216);  // 4096*384 ushort
  unsigned short* KSP = (unsigned short*)(A0 + 16777216 + 786432);

  dim3 b256(256), b1024(1024);

  // 1) y1_qk = 1x1(x, qk_w) -> A0 (2,192,HW)
  conv1x1<<<dim3(256,2), b256, 0, stream>>>(x, 96L*HW, qk_w, A0, 192L*HW, 192, 0);
  // 2) qk = dw3x3(y1_qk) -> A1 (2,192,HW); q=ch[0:96), k=ch[96:192)
  dw3x3<<<dim3(256,192,2), b256, 0, stream>>>(A0, qk_dw, A1, 192);
  // 3) y1_v = 1x1(x, v_w) -> A0 (2,96,HW)
  conv1x1<<<dim3(256,2), b256, 0, stream>>>(x, 96L*HW, v_w, A0, 96L*HW, 96, 0);
  // 4) v_s = permute(dw3x3(y1_v)) -> d_out
  dw3x3_vs<<<dim3(1024,2), b256, 0, stream>>>(A0, v_dw, VS);
  // 5) q2pre = 1x1(q, q2_w) -> A0 (2,192,HW)
  conv1x1<<<dim3(256,2), b256, 0, stream>>>(A1, 192L*HW, q2_w, A0, 192L*HW, 192, 0);
  // 6) qd = dw4x4s4(q2pre)
  dw4x4s4<<<dim3(16,192,2), b256, 0, stream>>>(A0, q2_dw, QD);
  // 7) k2pre = 1x1(k, k2_w) -> A0
  conv1x1<<<dim3(256,2), b256, 0, stream>>>(A1 + 96L*HW, 192L*HW, k2_w, A0, 192L*HW, 192, 0);
  // 8) kd = dw4x4s4(k2pre)
  dw4x4s4<<<dim3(16,192,2), b256, 0, stream>>>(A0, k2_dw, KD);
  // 9/10) l2norm + transpose -> qn (ws), kn (d_out k_s)
  l2n192<<<dim3(2048), b256, 0, stream>>>(QD, QN);
  l2n192<<<dim3(2048), b256, 0, stream>>>(KD, KS);
  // 11) attention, per batch (attn materialized in A0[0:16.7M])
  for (int b = 0; b < 2; b++) {
    bf16split<<<dim3(3072), b256, 0, stream>>>(QN + (long)b*786432, QSP);
    bf16split<<<dim3(3072), b256, 0, stream>>>(KS + (long)b*786432, KSP);
    attn_qk_mfma<<<dim3(32,32), b256, 0, stream>>>(QSP, KSP, A0, sab_temp);
    attn_out_k<<<dim3(4096), b256, 0, stream>>>(
        A0, VS + (long)b*6291456, A1 + (long)b*6291456);
  }
  // 12) aligned = 1x1(permuted attn-out, proj_w) -> A0[0:12.58M]
  conv1x1<<<dim3(256,2), b256, 0, stream>>>(A1, 6291456L, proj_w, A0, 96L*HW, 96, 1);
  // 13-15) fhr qkv: three sequential 96-ch paths
  float* PRE  = A0 + 12582912;
  float* DW1  = A1 + 12582912;
  float* Q2NB = A1;
  // q2
  conv1x1<<<dim3(256,2), b256, 0, stream>>>(A0, 96L*HW, fqkv_w,        PRE, 96L*HW, 96, 0);
  dw3x3<<<dim3(256,96,2), b256, 0, stream>>>(PRE, fqkv_dw,        DW1, 96);
  l2n_sp<<<dim3(96,2), b1024, 0, stream>>>(DW1, Q2NB);
  // k2
  conv1x1<<<dim3(256,2), b256, 0, stream>>>(A0, 96L*HW, fqkv_w +  9216, PRE, 96L*HW, 96, 0);
  dw3x3<<<dim3(256,96,2), b256, 0, stream>>>(PRE, fqkv_dw +  864, DW1, 96);
  l2n_sp<<<dim3(96,2), b1024, 0, stream>>>(DW1, K2N);
  // v2 (raw dw output is the v2 output layout directly)
  conv1x1<<<dim3(256,2), b256, 0, stream>>>(A0, 96L*HW, fqkv_w + 18432, PRE, 96L*HW, 96, 0);
  dw3x3<<<dim3(256,96,2), b256, 0, stream>>>(PRE, fqkv_dw + 1728, V2, 96);
  // 16) a2 = softmax(q2n.k2n^T * fhr_temp)
  a2_kern<<<dim3(12,8,2), b256, 0, stream>>>(Q2NB, K2N, fhr_temp, A2S);
  // 17) o2pre = a2 @ v2 -> A0
  o2pre_kern<<<dim3(256,16), b256, 0, stream>>>(A2S, V2, A0);
  // 18) o2 = 1x1(o2pre, fproj_w) -> d_out
  conv1x1<<<dim3(256,2), b256, 0, stream>>>(A0, 96L*HW, fproj_w, O2, 96L*HW, 96, 0);
}

// Round 5
// 1886.321 us; speedup vs baseline: 2.8922x; 1.0606x over previous
//
#include <hip/hip_runtime.h>
#include <hip/hip_bf16.h>
#include <math.h>

#define HW 65536L

typedef __attribute__((ext_vector_type(8))) short bf16x8;
typedef __attribute__((ext_vector_type(4))) float f32x4;

__device__ __forceinline__ int iabs_(int v) { return v < 0 ? -v : v; }

// ---------------- conv 1x1 (Cin=96), register-resident, no LDS ----------------
__global__ __launch_bounds__(256) void conv1x1(
    const float* __restrict__ in, long in_bstride,
    const float* __restrict__ w,
    float* __restrict__ out, long out_bstride,
    int Cout, int mode)
{
  const int t = threadIdx.x;
  const int p = blockIdx.x * 256 + t;
  const int b = blockIdx.y;
  float x[96];
  if (mode == 0) {
    const float* src = in + (long)b * in_bstride + p;
    #pragma unroll
    for (int c = 0; c < 96; c++) x[c] = src[(long)c * HW];
  } else {
    // input is attention output (B,4096,1536); spatial pixel p maps to
    // att[n][blk*96+ci], n=(y%64)*64+(x%64), blk=(y/64)*4+(x/64)
    const int py = p >> 8, px = p & 255;
    const float* src = in + (long)b * in_bstride
        + ((long)((py & 63)*64 + (px & 63)) * 16 + ((py >> 6)*4 + (px >> 6))) * 96;
    #pragma unroll
    for (int cb = 0; cb < 24; cb++) {
      float4 v = *(const float4*)&src[cb*4];
      x[cb*4+0] = v.x; x[cb*4+1] = v.y; x[cb*4+2] = v.z; x[cb*4+3] = v.w;
    }
  }
  float* dst = out + (long)b * out_bstride + p;
  const int ng = Cout >> 3;
  for (int g = 0; g < ng; g++) {
    const float* wg = w + g*8*96;
    float acc[8];
    #pragma unroll
    for (int j = 0; j < 8; j++) acc[j] = 0.f;
    #pragma unroll
    for (int k = 0; k < 96; k++) {
      float xv = x[k];
      #pragma unroll
      for (int j = 0; j < 8; j++) acc[j] = fmaf(wg[j*96 + k], xv, acc[j]);
    }
    #pragma unroll
    for (int j = 0; j < 8; j++) dst[(long)(g*8 + j) * HW] = acc[j];
  }
}

// ---------------- depthwise 3x3 pad 1 ----------------
__global__ __launch_bounds__(256) void dw3x3(
    const float* __restrict__ in, const float* __restrict__ w,
    float* __restrict__ out, int CH)
{
  const int t = threadIdx.x;
  const int p = blockIdx.x * 256 + t;
  const int ch = blockIdx.y, b = blockIdx.z;
  const int y = p >> 8, x = p & 255;
  const float* ip = in + (long)(b*CH + ch) * HW;
  const float* wp = w + ch*9;
  float acc = 0.f;
  #pragma unroll
  for (int dy = -1; dy <= 1; dy++) {
    int yy = y + dy;
    if (yy < 0 || yy > 255) continue;
    #pragma unroll
    for (int dx = -1; dx <= 1; dx++) {
      int xx = x + dx;
      if (xx < 0 || xx > 255) continue;
      acc = fmaf(ip[yy*256 + xx], wp[(dy+1)*3 + (dx+1)], acc);
    }
  }
  out[(long)(b*CH + ch) * HW + p] = acc;
}

// ------- depthwise 3x3 fused with v_s permutation (coalesced, LDS reorder) ----
__global__ __launch_bounds__(256) void dw3x3_vs(
    const float* __restrict__ in, const float* __restrict__ w,
    float* __restrict__ vs)
{
  __shared__ float tile[96*65];
  const int t = threadIdx.x;
  const int gb = blockIdx.x;          // 0..1023 = y*4 + xb
  const int b = blockIdx.y;
  const int y = gb >> 2, xb = gb & 3;
  const int x0 = xb * 64;
  #pragma unroll
  for (int i = 0; i < 24; i++) {
    const int idx = i*256 + t;
    const int ci = idx >> 6, xl = idx & 63;
    const float* ip = in + ((long)b*96 + ci) * HW;
    const float* wp = w + ci*9;
    const int x = x0 + xl;
    float acc = 0.f;
    #pragma unroll
    for (int dy = -1; dy <= 1; dy++) {
      const int yy = y + dy;
      if (yy < 0 || yy > 255) continue;
      const float* rp = ip + yy*256;
      #pragma unroll
      for (int dx = -1; dx <= 1; dx++) {
        const int xx = x + dx;
        if (xx < 0 || xx > 255) continue;
        acc = fmaf(rp[xx], wp[(dy+1)*3 + (dx+1)], acc);
      }
    }
    tile[ci*65 + xl] = acc;
  }
  __syncthreads();
  const int blk = (y >> 6)*4 + xb;
  float* obase = vs + ((long)b*4096 + (long)(y & 63)*64) * 1536 + blk*96;
  #pragma unroll
  for (int i = 0; i < 24; i++) {
    const int idx = i*256 + t;
    const int nl = idx / 96, ci = idx % 96;
    obase[(long)nl*1536 + ci] = tile[ci*65 + nl];
  }
}

// ---------------- depthwise 4x4 stride 4 pad 1 (256->64) ----------------
__global__ __launch_bounds__(256) void dw4x4s4(
    const float* __restrict__ in, const float* __restrict__ w,
    float* __restrict__ out)
{
  const int t = threadIdx.x;
  const int op = blockIdx.x * 256 + t;
  const int ch = blockIdx.y, b = blockIdx.z;
  const int oy = op >> 6, ox = op & 63;
  const float* ip = in + (long)(b*192 + ch) * HW;
  const float* wp = w + ch*16;
  float acc = 0.f;
  #pragma unroll
  for (int ty = 0; ty < 4; ty++) {
    int iy = 4*oy + ty - 1;
    if (iy < 0 || iy > 255) continue;
    #pragma unroll
    for (int tx = 0; tx < 4; tx++) {
      int ix = 4*ox + tx - 1;
      if (ix < 0 || ix > 255) continue;
      acc = fmaf(ip[iy*256 + ix], wp[ty*4 + tx], acc);
    }
  }
  out[(long)(b*192 + ch) * 4096 + op] = acc;
}

// ---------------- l2 norm over 192 channels + transpose to (B,4096,192) ----
__global__ __launch_bounds__(256) void l2n192(
    const float* __restrict__ in, float* __restrict__ out)
{
  const int t = threadIdx.x;
  const int wid = t >> 6, lane = t & 63;
  const int gw = blockIdx.x * 4 + wid;      // 0..8191
  const int b = gw >> 12, n = gw & 4095;
  const float* ip = in + (long)b * 786432;  // 192*4096
  float v0 = ip[(long)(lane      ) * 4096 + n];
  float v1 = ip[(long)(lane +  64) * 4096 + n];
  float v2 = ip[(long)(lane + 128) * 4096 + n];
  float ss = v0*v0 + v1*v1 + v2*v2;
  #pragma unroll
  for (int s = 1; s < 64; s <<= 1) ss += __shfl_xor(ss, s, 64);
  float nrm = fmaxf(sqrtf(ss), 1e-12f);
  float* op = out + ((long)b*4096 + n) * 192;
  op[lane      ] = v0 / nrm;
  op[lane +  64] = v1 / nrm;
  op[lane + 128] = v2 / nrm;
}

// ---------------- split fp32 -> (hi,lo) bf16 planes: (4096,192) -> (4096,384) -
__global__ __launch_bounds__(256) void bf16split(
    const float* __restrict__ in, unsigned short* __restrict__ outp)
{
  const int i = blockIdx.x * 256 + threadIdx.x;   // 0..786431
  const int n = i / 192, k = i % 192;
  float f = in[i];
  __hip_bfloat16 h = __float2bfloat16(f);
  float hf = __bfloat162float(h);
  __hip_bfloat16 l = __float2bfloat16(f - hf);
  outp[(long)n*384 + k]       = *(unsigned short*)&h;
  outp[(long)n*384 + 192 + k] = *(unsigned short*)&l;
}

// ---------------- attention QK^T via split-bf16 MFMA (one batch) ------------
#define LDSROW 40   // ushorts per staged row (32 data + 8 pad) = 80 B
__global__ __launch_bounds__(256) void attn_qk_mfma(
    const unsigned short* __restrict__ Qsp, const unsigned short* __restrict__ Ksp,
    float* __restrict__ attn, const float* __restrict__ tp)
{
  __shared__ unsigned short qs[256*LDSROW];   // [hl*128+row][LDSROW]
  __shared__ unsigned short ks[256*LDSROW];
  const int t = threadIdx.x;
  const int lane = t & 63, w = t >> 6;
  const int n0 = blockIdx.x * 128;   // Q rows
  const int m0 = blockIdx.y * 128;   // K rows
  const int wr = (w >> 1) * 64, wc = (w & 1) * 64;
  f32x4 acc[4][4] = {};
  const int srow = t & 127;
  const int shl  = t >> 7;           // 0 = hi plane, 1 = lo plane
  const unsigned short* qsrc = Qsp + (long)(n0 + srow) * 384 + shl * 192;
  const unsigned short* ksrc = Ksp + (long)(m0 + srow) * 384 + shl * 192;
  unsigned short* qdst = qs + (shl*128 + srow) * LDSROW;
  unsigned short* kdst = ks + (shl*128 + srow) * LDSROW;
  const int fr = lane & 15;
  const int fk = lane >> 4;
  for (int s = 0; s < 6; s++) {
    __syncthreads();
    #pragma unroll
    for (int j = 0; j < 4; j++) {
      *(bf16x8*)(qdst + j*8) = *(const bf16x8*)(qsrc + s*32 + j*8);
      *(bf16x8*)(kdst + j*8) = *(const bf16x8*)(ksrc + s*32 + j*8);
    }
    __syncthreads();
    bf16x8 ah[4], al[4], bh[4], bl[4];
    #pragma unroll
    for (int i = 0; i < 4; i++) {
      ah[i] = *(const bf16x8*)(qs + (      wr + i*16 + fr) * LDSROW + fk*8);
      al[i] = *(const bf16x8*)(qs + (128 + wr + i*16 + fr) * LDSROW + fk*8);
      bh[i] = *(const bf16x8*)(ks + (      wc + i*16 + fr) * LDSROW + fk*8);
      bl[i] = *(const bf16x8*)(ks + (128 + wc + i*16 + fr) * LDSROW + fk*8);
    }
    #pragma unroll
    for (int i = 0; i < 4; i++)
      #pragma unroll
      for (int j = 0; j < 4; j++) {
        acc[i][j] = __builtin_amdgcn_mfma_f32_16x16x32_bf16(ah[i], bh[j], acc[i][j], 0, 0, 0);
        acc[i][j] = __builtin_amdgcn_mfma_f32_16x16x32_bf16(ah[i], bl[j], acc[i][j], 0, 0, 0);
        acc[i][j] = __builtin_amdgcn_mfma_f32_16x16x32_bf16(al[i], bh[j], acc[i][j], 0, 0, 0);
      }
  }
  const float temp = tp[0];
  #pragma unroll
  for (int i = 0; i < 4; i++)
    #pragma unroll
    for (int j = 0; j < 4; j++)
      #pragma unroll
      for (int r = 0; r < 4; r++) {
        const int nn = n0 + wr + i*16 + (lane >> 4)*4 + r;  // Q row (M)
        const int mm = m0 + wc + j*16 + (lane & 15);        // K row (N)
        attn[(long)nn*4096 + mm] = acc[i][j][r] * temp;
      }
}

// ------- top-5 + local mask + softmax + sparse out (one batch, one row/blk) -
__global__ __launch_bounds__(256) void attn_out_k(
    const float* __restrict__ attn, const float* __restrict__ vs,
    float* __restrict__ outr)
{
  __shared__ float row[4096];
  __shared__ float top5[256*5];
  __shared__ int   lm[4096];
  __shared__ float lw[4096];
  __shared__ float redf[8];
  __shared__ int   scan[256];
  const int t = threadIdx.x;
  const int n = blockIdx.x;
  const float* ar = attn + (long)n * 4096;
  #pragma unroll
  for (int k = 0; k < 16; k++) row[k*256 + t] = ar[k*256 + t];
  __syncthreads();
  float t0=-INFINITY,t1=-INFINITY,t2=-INFINITY,t3=-INFINITY,t4=-INFINITY;
  #pragma unroll
  for (int k = 0; k < 16; k++) {
    float v = row[k*256 + t];
    if (v > t4) {
      if (v > t0)      { t4=t3; t3=t2; t2=t1; t1=t0; t0=v; }
      else if (v > t1) { t4=t3; t3=t2; t2=t1; t1=v; }
      else if (v > t2) { t4=t3; t3=t2; t2=v; }
      else if (v > t3) { t4=t3; t3=v; }
      else             { t4=v; }
    }
  }
  top5[t*5+0]=t0; top5[t*5+1]=t1; top5[t*5+2]=t2; top5[t*5+3]=t3; top5[t*5+4]=t4;
  __syncthreads();
  for (int s = 128; s >= 1; s >>= 1) {
    if (t < s) {
      float* A = &top5[t*5];
      const float* B = &top5[(t+s)*5];
      float m[5]; int i = 0, j = 0;
      #pragma unroll
      for (int k = 0; k < 5; k++) {
        float av = A[i], bv = B[j];
        if (av >= bv) { m[k] = av; i++; } else { m[k] = bv; j++; }
      }
      #pragma unroll
      for (int k = 0; k < 5; k++) A[k] = m[k];
    }
    __syncthreads();
  }
  const float kth = top5[4];
  const int y = n >> 6, x = n & 63;
  int myc = 0;
  float wmax = -INFINITY;
  #pragma unroll
  for (int k = 0; k < 16; k++) {
    int m = k*256 + t;
    float a = row[m];
    int c = ((a >= kth) ? 1 : 0) +
            (((iabs_(y - (m >> 6)) + iabs_(x - (m & 63))) <= 4) ? 1 : 0);
    float wv = a * (float)c;
    if (wv != 0.0f) { myc++; wmax = fmaxf(wmax, wv); }
  }
  scan[t] = myc;
  __syncthreads();
  for (int s = 1; s < 256; s <<= 1) {
    int v = (t >= s) ? scan[t-s] : 0;
    __syncthreads();
    scan[t] += v;
    __syncthreads();
  }
  const int base = scan[t] - myc;
  const int cnt = scan[255];
  {
    int idx = base;
    #pragma unroll
    for (int k = 0; k < 16; k++) {
      int m = k*256 + t;
      float a = row[m];
      int c = ((a >= kth) ? 1 : 0) +
              (((iabs_(y - (m >> 6)) + iabs_(x - (m & 63))) <= 4) ? 1 : 0);
      float wv = a * (float)c;
      if (wv != 0.0f) { lm[idx] = m; lw[idx] = wv; idx++; }
    }
  }
  #pragma unroll
  for (int s = 1; s < 64; s <<= 1) wmax = fmaxf(wmax, __shfl_xor(wmax, s, 64));
  if ((t & 63) == 0) redf[t >> 6] = wmax;
  __syncthreads();
  const float gmax = fmaxf(fmaxf(redf[0], redf[1]), fmaxf(redf[2], redf[3]));
  __syncthreads();
  float ps = 0.f;
  for (int i = t; i < cnt; i += 256) ps += expf(lw[i] - gmax);
  #pragma unroll
  for (int s = 1; s < 64; s <<= 1) ps += __shfl_xor(ps, s, 64);
  if ((t & 63) == 0) redf[4 + (t >> 6)] = ps;
  __syncthreads();
  const float S = redf[4] + redf[5] + redf[6] + redf[7];
  const float invS = 1.0f / S;
  float a0=0,a1=0,a2=0,a3=0,a4=0,a5=0;
  for (int e = 0; e < cnt; e++) {
    float se = expf(lw[e] - gmax) * invS;
    const float* vr = vs + (long)lm[e] * 1536;
    a0 = fmaf(se, vr[          t], a0);
    a1 = fmaf(se, vr[ 256 + t], a1);
    a2 = fmaf(se, vr[ 512 + t], a2);
    a3 = fmaf(se, vr[ 768 + t], a3);
    a4 = fmaf(se, vr[1024 + t], a4);
    a5 = fmaf(se, vr[1280 + t], a5);
  }
  float* orow = outr + (long)n * 1536;
  orow[          t] = a0;
  orow[ 256 + t] = a1;
  orow[ 512 + t] = a2;
  orow[ 768 + t] = a3;
  orow[1024 + t] = a4;
  orow[1280 + t] = a5;
}

// ---------------- per-channel l2 norm over 65536 (fhr q2/k2) ----------------
__global__ __launch_bounds__(1024) void l2n_sp(
    const float* __restrict__ in, float* __restrict__ out)
{
  const int ch = blockIdx.x, b = blockIdx.y, t = threadIdx.x;
  const float* ip = in + ((long)b*96 + ch) * HW;
  float ss = 0.f;
  for (int i = t; i < 65536; i += 1024) { float v = ip[i]; ss = fmaf(v, v, ss); }
  __shared__ float red[16];
  #pragma unroll
  for (int s = 1; s < 64; s <<= 1) ss += __shfl_xor(ss, s, 64);
  if ((t & 63) == 0) red[t >> 6] = ss;
  __syncthreads();
  if (t == 0) {
    float s2 = 0.f;
    for (int i = 0; i < 16; i++) s2 += red[i];
    red[0] = fmaxf(sqrtf(s2), 1e-12f);
  }
  __syncthreads();
  const float nrm = red[0];
  float* op = out + ((long)b*96 + ch) * HW;
  for (int i = t; i < 65536; i += 1024) op[i] = ip[i] / nrm;
}

// -------- a2 stage 1: partial Gram (12x12) over 4096-elem chunks ------------
#define A2_NCH 16
__global__ __launch_bounds__(256) void a2_part(
    const float* __restrict__ q2n, const float* __restrict__ k2n,
    float* __restrict__ part)
{
  __shared__ float sh[24*260];
  const int t = threadIdx.x;
  const int ch = blockIdx.x, h = blockIdx.y, b = blockIdx.z;
  const long base = ((long)b*96 + h*12) * HW + ch*4096;
  const int c = t / 12, d = t - (t/12)*12;   // valid for t<144
  float acc = 0.f;
  for (int sub = 0; sub < 16; sub++) {
    __syncthreads();
    #pragma unroll
    for (int j = 0; j < 6; j++) {
      const int v = j*256 + t;          // 0..1535
      const int row = v >> 6;           // 0..23
      const int col4 = v & 63;
      const float* src = (row < 12)
        ? q2n + base + (long)row*HW + sub*256 + col4*4
        : k2n + base + (long)(row-12)*HW + sub*256 + col4*4;
      *(float4*)&sh[row*260 + col4*4] = *(const float4*)src;
    }
    __syncthreads();
    if (t < 144) {
      const float* qr = &sh[c*260];
      const float* kr = &sh[(12+d)*260];
      #pragma unroll
      for (int i4 = 0; i4 < 64; i4++) {
        float4 qv = *(const float4*)&qr[i4*4];
        float4 kv = *(const float4*)&kr[i4*4];
        acc = fmaf(qv.x, kv.x, acc);
        acc = fmaf(qv.y, kv.y, acc);
        acc = fmaf(qv.z, kv.z, acc);
        acc = fmaf(qv.w, kv.w, acc);
      }
    }
  }
  if (t < 144)
    part[(((long)b*8 + h)*A2_NCH + ch)*144 + t] = acc;
}

// -------- a2 stage 2: deterministic reduce + temp scale + softmax(12) -------
__global__ __launch_bounds__(256) void a2_fin(
    const float* __restrict__ part, const float* __restrict__ temp,
    float* __restrict__ a2s)
{
  __shared__ float m[144];
  const int t = threadIdx.x;
  const int h = blockIdx.x, b = blockIdx.y;
  if (t < 144) {
    float s = 0.f;
    const float* pp = part + (((long)b*8 + h)*A2_NCH)*144 + t;
    #pragma unroll
    for (int ch = 0; ch < A2_NCH; ch++) s += pp[ch*144];
    m[t] = s * temp[h];
  }
  __syncthreads();
  if (t < 12) {
    float mx = -INFINITY;
    #pragma unroll
    for (int d = 0; d < 12; d++) mx = fmaxf(mx, m[t*12+d]);
    float e[12], sum = 0.f;
    #pragma unroll
    for (int d = 0; d < 12; d++) { e[d] = expf(m[t*12+d]-mx); sum += e[d]; }
    float inv = 1.0f/sum;
    float* op = a2s + (((long)b*8 + h)*12 + t)*12;
    #pragma unroll
    for (int d = 0; d < 12; d++) op[d] = e[d]*inv;
  }
}

// ---------------- o2pre = a2 @ v2 ----------------
__global__ __launch_bounds__(256) void o2pre_kern(
    const float* __restrict__ a2s, const float* __restrict__ v2,
    float* __restrict__ o2p)
{
  const int t = threadIdx.x;
  const int n = blockIdx.x * 256 + t;
  const int bh = blockIdx.y, b = bh >> 3, h = bh & 7;
  const float* a = a2s + (long)bh * 144;
  const float* vb = v2 + ((long)b*96 + h*12) * HW;
  float vv[12];
  #pragma unroll
  for (int d = 0; d < 12; d++) vv[d] = vb[(long)d*HW + n];
  float* ob = o2p + ((long)b*96 + h*12) * HW;
  #pragma unroll
  for (int c = 0; c < 12; c++) {
    float s = 0.f;
    #pragma unroll
    for (int d = 0; d < 12; d++) s = fmaf(a[c*12 + d], vv[d], s);
    ob[(long)c*HW + n] = s;
  }
}

extern "C" void kernel_launch(void* const* d_in, const int* in_sizes, int n_in,
                              void* d_out, int out_size, void* d_ws, size_t ws_size,
                              hipStream_t stream) {
  const float* x        = (const float*)d_in[0];
  const float* qk_w     = (const float*)d_in[1];
  const float* qk_dw    = (const float*)d_in[2];
  const float* v_w      = (const float*)d_in[3];
  const float* v_dw     = (const float*)d_in[4];
  const float* k2_w     = (const float*)d_in[5];
  const float* k2_dw    = (const float*)d_in[6];
  const float* q2_w     = (const float*)d_in[7];
  const float* q2_dw    = (const float*)d_in[8];
  const float* proj_w   = (const float*)d_in[9];
  const float* sab_temp = (const float*)d_in[10];
  const float* fqkv_w   = (const float*)d_in[11];
  const float* fqkv_dw  = (const float*)d_in[12];
  const float* fproj_w  = (const float*)d_in[13];
  const float* fhr_temp = (const float*)d_in[14];
  float* out = (float*)d_out;
  float* ws  = (float*)d_ws;

  // d_out regions (floats)
  float* O2  = out;               // (2,96,256,256)
  float* KS  = out + 12582912;    // (2,1,1,4096,192)  = normalized k
  float* VS  = out + 14155776;    // (2,1,1,4096,1536) = permuted v
  float* K2N = out + 26738688;    // (2,8,12,65536)    = normalized k2
  float* V2  = out + 39321600;    // (2,8,12,65536)    = raw v2

  // ws arena (floats)
  float* A0   = ws;                // 25165824 (attn uses first 16777216)
  float* A1   = ws + 25165824;     // 25165824
  float* QD   = ws + 50331648;     // 1572864
  float* KD   = ws + 51904512;     // 1572864
  float* QN   = ws + 53477376;     // 1572864
  float* A2S  = ws + 55050240;     // 2304
  float* PART = ws + 55052544;     // 36864
  unsigned short* QSP = (unsigned short*)(A0 + 16777216);  // 4096*384 ushort
  unsigned short* KSP = (unsigned short*)(A0 + 16777216 + 786432);

  dim3 b256(256), b1024(1024);

  // 1) y1_qk = 1x1(x, qk_w) -> A0 (2,192,HW)
  conv1x1<<<dim3(256,2), b256, 0, stream>>>(x, 96L*HW, qk_w, A0, 192L*HW, 192, 0);
  // 2) qk = dw3x3(y1_qk) -> A1 (2,192,HW); q=ch[0:96), k=ch[96:192)
  dw3x3<<<dim3(256,192,2), b256, 0, stream>>>(A0, qk_dw, A1, 192);
  // 3) y1_v = 1x1(x, v_w) -> A0 (2,96,HW)
  conv1x1<<<dim3(256,2), b256, 0, stream>>>(x, 96L*HW, v_w, A0, 96L*HW, 96, 0);
  // 4) v_s = permute(dw3x3(y1_v)) -> d_out
  dw3x3_vs<<<dim3(1024,2), b256, 0, stream>>>(A0, v_dw, VS);
  // 5) q2pre = 1x1(q, q2_w) -> A0 (2,192,HW)
  conv1x1<<<dim3(256,2), b256, 0, stream>>>(A1, 192L*HW, q2_w, A0, 192L*HW, 192, 0);
  // 6) qd = dw4x4s4(q2pre)
  dw4x4s4<<<dim3(16,192,2), b256, 0, stream>>>(A0, q2_dw, QD);
  // 7) k2pre = 1x1(k, k2_w) -> A0
  conv1x1<<<dim3(256,2), b256, 0, stream>>>(A1 + 96L*HW, 192L*HW, k2_w, A0, 192L*HW, 192, 0);
  // 8) kd = dw4x4s4(k2pre)
  dw4x4s4<<<dim3(16,192,2), b256, 0, stream>>>(A0, k2_dw, KD);
  // 9/10) l2norm + transpose -> qn (ws), kn (d_out k_s)
  l2n192<<<dim3(2048), b256, 0, stream>>>(QD, QN);
  l2n192<<<dim3(2048), b256, 0, stream>>>(KD, KS);
  // 11) attention, per batch (attn materialized in A0[0:16.7M])
  for (int b = 0; b < 2; b++) {
    bf16split<<<dim3(3072), b256, 0, stream>>>(QN + (long)b*786432, QSP);
    bf16split<<<dim3(3072), b256, 0, stream>>>(KS + (long)b*786432, KSP);
    attn_qk_mfma<<<dim3(32,32), b256, 0, stream>>>(QSP, KSP, A0, sab_temp);
    attn_out_k<<<dim3(4096), b256, 0, stream>>>(
        A0, VS + (long)b*6291456, A1 + (long)b*6291456);
  }
  // 12) aligned = 1x1(permuted attn-out, proj_w) -> A0[0:12.58M]
  conv1x1<<<dim3(256,2), b256, 0, stream>>>(A1, 6291456L, proj_w, A0, 96L*HW, 96, 1);
  // 13-15) fhr qkv: three sequential 96-ch paths
  float* PRE  = A0 + 12582912;
  float* DW1  = A1 + 12582912;
  float* Q2NB = A1;
  // q2
  conv1x1<<<dim3(256,2), b256, 0, stream>>>(A0, 96L*HW, fqkv_w,        PRE, 96L*HW, 96, 0);
  dw3x3<<<dim3(256,96,2), b256, 0, stream>>>(PRE, fqkv_dw,        DW1, 96);
  l2n_sp<<<dim3(96,2), b1024, 0, stream>>>(DW1, Q2NB);
  // k2
  conv1x1<<<dim3(256,2), b256, 0, stream>>>(A0, 96L*HW, fqkv_w +  9216, PRE, 96L*HW, 96, 0);
  dw3x3<<<dim3(256,96,2), b256, 0, stream>>>(PRE, fqkv_dw +  864, DW1, 96);
  l2n_sp<<<dim3(96,2), b1024, 0, stream>>>(DW1, K2N);
  // v2 (raw dw output is the v2 output layout directly)
  conv1x1<<<dim3(256,2), b256, 0, stream>>>(A0, 96L*HW, fqkv_w + 18432, PRE, 96L*HW, 96, 0);
  dw3x3<<<dim3(256,96,2), b256, 0, stream>>>(PRE, fqkv_dw + 1728, V2, 96);
  // 16) a2 = softmax(q2n.k2n^T * fhr_temp), two-stage deterministic
  a2_part<<<dim3(A2_NCH,8,2), b256, 0, stream>>>(Q2NB, K2N, PART);
  a2_fin<<<dim3(8,2), b256, 0, stream>>>(PART, fhr_temp, A2S);
  // 17) o2pre = a2 @ v2 -> A0
  o2pre_kern<<<dim3(256,16), b256, 0, stream>>>(A2S, V2, A0);
  // 18) o2 = 1x1(o2pre, fproj_w) -> d_out
  conv1x1<<<dim3(256,2), b256, 0, stream>>>(A0, 96L*HW, fproj_w, O2, 96L*HW, 96, 0);
}